// Round 1
// baseline (3184.350 us; speedup 1.0000x reference)
//
#include <hip/hip_runtime.h>
#include <math.h>

#define NN 50000
#define NE 800000

// ---------------------------------------------------------------------------
// Column stats (sum, sumsq) over rows for BN (training mode, biased var).
// block 256 = (256/C) row-lanes x C cols; partial per thread, LDS reduce,
// one atomicAdd per column per block.
template<int C>
__global__ void colstats(const float* __restrict__ x, int rows,
                         float* __restrict__ sum, float* __restrict__ sq) {
  constexpr int RL = 256 / C;
  int c = threadIdx.x % C;
  int r0 = threadIdx.x / C;
  float s = 0.f, q = 0.f;
  for (int r = blockIdx.x * RL + r0; r < rows; r += gridDim.x * RL) {
    float v = x[(size_t)r * C + c];
    s += v; q += v * v;
  }
  __shared__ float ls[256], lq[256];
  ls[threadIdx.x] = s; lq[threadIdx.x] = q;
  __syncthreads();
  if (r0 == 0) {
    #pragma unroll
    for (int i = 1; i < RL; ++i) { s += ls[i * C + c]; q += lq[i * C + c]; }
    atomicAdd(&sum[c], s);
    atomicAdd(&sq[c], q);
  }
}

__global__ void finalize_sb(const float* __restrict__ sum, const float* __restrict__ sq,
                            float inv_rows,
                            const float* __restrict__ g, const float* __restrict__ b,
                            float* __restrict__ scale, float* __restrict__ bias, int C) {
  int c = threadIdx.x;
  if (c < C) {
    float mu = sum[c] * inv_rows;
    float var = sq[c] * inv_rows - mu * mu;
    float sc = g[c] * rsqrtf(var + 1e-5f);
    scale[c] = sc;
    bias[c] = b[c] - mu * sc;
  }
}

// h = relu(x*scale + bias), row width 64, vectorized float4. grid*256 == NN*16.
__global__ void bn_relu64(const float* __restrict__ x, const float* __restrict__ scale,
                          const float* __restrict__ bias, float* __restrict__ out) {
  int i = blockIdx.x * 256 + threadIdx.x;      // float4 index
  int c4 = (i & 15) * 4;
  float4 v = ((const float4*)x)[i];
  float4 s = *(const float4*)(scale + c4);
  float4 b = *(const float4*)(bias + c4);
  float4 r;
  r.x = fmaxf(v.x * s.x + b.x, 0.f);
  r.y = fmaxf(v.y * s.y + b.y, 0.f);
  r.z = fmaxf(v.z * s.z + b.z, 0.f);
  r.w = fmaxf(v.w * s.w + b.w, 0.f);
  ((float4*)out)[i] = r;
}

// ---------------------------------------------------------------------------
// CSR build: count -> scan -> fill (grid 3125*256 == NE exactly)
__global__ void count_edges(const int* __restrict__ dst, int* __restrict__ cnt) {
  int e = blockIdx.x * 256 + threadIdx.x;
  atomicAdd(&cnt[dst[e]], 1);
}

__global__ void scan_offsets(const int* __restrict__ cnt, int* __restrict__ off) {
  __shared__ int buf[1024];
  __shared__ int carry;
  int tid = threadIdx.x;
  if (tid == 0) carry = 0;
  __syncthreads();
  for (int base = 0; base < NN; base += 1024) {
    int i = base + tid;
    int v = (i < NN) ? cnt[i] : 0;
    buf[tid] = v;
    __syncthreads();
    for (int d = 1; d < 1024; d <<= 1) {
      int t = (tid >= d) ? buf[tid - d] : 0;
      __syncthreads();
      buf[tid] += t;
      __syncthreads();
    }
    int incl = buf[tid];
    int cr = carry;
    __syncthreads();
    if (i < NN) off[i] = cr + incl - v;   // exclusive
    if (tid == 1023) carry = cr + incl;
    __syncthreads();
  }
  if (tid == 0) off[NN] = NE;
}

__global__ void fill_sorted(const int* __restrict__ dst, const int* __restrict__ off,
                            int* __restrict__ cursor, int* __restrict__ sorted) {
  int e = blockIdx.x * 256 + threadIdx.x;
  int n = dst[e];
  int p = atomicAdd(&cursor[n], 1);
  sorted[off[n] + p] = e;
}

// ---------------------------------------------------------------------------
// Fused 2-layer edge MLP: z(192) -> relu(W1 z + b1)(128) -> W2 h + b2 (64).
// lane = edge (64 edges/wave, 256 edges/block). Activations staged in
// thread-private LDS rows (stride 33 -> conflict-free); weights wave-uniform
// (scalar loads); 128 fp32 accumulators, all statically indexed.
template<bool RELU_H>
__global__ __launch_bounds__(256, 2)
void edge_mlp(const float* __restrict__ hbase, const int* __restrict__ ei,
              const float* __restrict__ ea,
              const float* __restrict__ vsc, const float* __restrict__ vbi,
              const float* __restrict__ W1, const float* __restrict__ B1,
              const float* __restrict__ W2, const float* __restrict__ B2,
              float* __restrict__ out, int first_is_dst) {
  __shared__ float zl[4][64][33];
  int lane = threadIdx.x & 63;
  int wid = threadIdx.x >> 6;
  int e = blockIdx.x * 256 + threadIdx.x;   // exact, no guard (NE = 3125*256)
  float* zrow = &zl[wid][lane][0];

  int src = ei[e];
  int dst = ei[NE + e];
  int nA = first_is_dst ? dst : src;
  int nB = first_is_dst ? src : dst;

  float acc[128];
  #pragma unroll
  for (int j = 0; j < 128; ++j) acc[j] = B1[j];

  // layer 1: K=192 in 6 chunks of 32
  #pragma unroll
  for (int c = 0; c < 6; ++c) {
    if (c < 4) {
      int node = (c < 2) ? nA : nB;
      const float4* p = (const float4*)(hbase + (size_t)node * 64 + (c & 1) * 32);
      #pragma unroll
      for (int q = 0; q < 8; ++q) {
        float4 v = p[q];
        if (RELU_H) {
          v.x = fmaxf(v.x, 0.f); v.y = fmaxf(v.y, 0.f);
          v.z = fmaxf(v.z, 0.f); v.w = fmaxf(v.w, 0.f);
        }
        zrow[4*q+0] = v.x; zrow[4*q+1] = v.y; zrow[4*q+2] = v.z; zrow[4*q+3] = v.w;
      }
    } else {
      const float4* p = (const float4*)(ea + (size_t)e * 64 + (c & 1) * 32);
      #pragma unroll
      for (int q = 0; q < 8; ++q) {
        float4 v = p[q];
        int ci = (c & 1) * 32 + 4 * q;
        float4 s = *(const float4*)(vsc + ci);
        float4 b = *(const float4*)(vbi + ci);
        zrow[4*q+0] = fmaxf(v.x * s.x + b.x, 0.f);
        zrow[4*q+1] = fmaxf(v.y * s.y + b.y, 0.f);
        zrow[4*q+2] = fmaxf(v.z * s.z + b.z, 0.f);
        zrow[4*q+3] = fmaxf(v.w * s.w + b.w, 0.f);
      }
    }
    const float* wseg = W1 + (size_t)c * 32 * 128;
    #pragma unroll 1
    for (int k = 0; k < 32; ++k) {
      float zk = zrow[k];
      const float4* wr = (const float4*)(wseg + (size_t)k * 128);
      #pragma unroll
      for (int q = 0; q < 32; ++q) {
        float4 w = wr[q];
        acc[4*q+0] += zk * w.x;
        acc[4*q+1] += zk * w.y;
        acc[4*q+2] += zk * w.z;
        acc[4*q+3] += zk * w.w;
      }
    }
  }

  // layer 2: relu(acc) (128) -> 64, via LDS round-trip in chunks of 32
  float macc[64];
  #pragma unroll
  for (int f = 0; f < 64; ++f) macc[f] = B2[f];

  #pragma unroll
  for (int jc = 0; jc < 4; ++jc) {
    #pragma unroll
    for (int i = 0; i < 32; ++i) zrow[i] = fmaxf(acc[jc * 32 + i], 0.f);
    const float* w2c = W2 + (size_t)jc * 32 * 64;
    #pragma unroll 1
    for (int j = 0; j < 32; ++j) {
      float hj = zrow[j];
      const float4* wr = (const float4*)(w2c + (size_t)j * 64);
      #pragma unroll
      for (int q = 0; q < 16; ++q) {
        float4 w = wr[q];
        macc[4*q+0] += hj * w.x;
        macc[4*q+1] += hj * w.y;
        macc[4*q+2] += hj * w.z;
        macc[4*q+3] += hj * w.w;
      }
    }
  }

  float4* op = (float4*)(out + (size_t)e * 64);
  #pragma unroll
  for (int q = 0; q < 16; ++q) {
    float4 v;
    v.x = macc[4*q+0]; v.y = macc[4*q+1]; v.z = macc[4*q+2]; v.w = macc[4*q+3];
    op[q] = v;
  }
}

// ---------------------------------------------------------------------------
// Per-node online scatter-softmax + weighted aggregation. wave = node,
// lane = feature. msg[n,f] = sum(m*alpha) with alpha = softmax(m*t) over edges.
__global__ void node_softmax(const float* __restrict__ m, const int* __restrict__ off,
                             const int* __restrict__ sorted, const float* __restrict__ tptr,
                             float* __restrict__ msg) {
  int gw = (blockIdx.x * 256 + threadIdx.x) >> 6;
  int lane = threadIdx.x & 63;
  if (gw >= NN) return;
  float t = tptr[0];
  int beg = off[gw], end = off[gw + 1];
  float M = -1e30f, S = 0.f, Wn = 0.f;
  for (int i = beg; i < end; ++i) {
    int e = sorted[i];
    float mv = m[(size_t)e * 64 + lane];
    float s = mv * t;
    float Mn = fmaxf(M, s);
    float c = __expf(M - Mn);
    float p = __expf(s - Mn);
    S = S * c + p;
    Wn = Wn * c + mv * p;
    M = Mn;
  }
  msg[(size_t)gw * 64 + lane] = (end > beg) ? (Wn / S) : 0.f;
}

// ---------------------------------------------------------------------------
// Node GEMM, K=128 (2 chunks of 64... here 4 chunks of 32), OUT in {128,64}.
// MODE 0: u = [in0_row(64) | in1_row(64)] raw. MODE 1: u = relu(in0*sc+bi).
template<int MODE, int OUT>
__global__ __launch_bounds__(256, 2)
void node_gemm(const float* __restrict__ in0, const float* __restrict__ in1,
               const float* __restrict__ sc, const float* __restrict__ bi,
               const float* __restrict__ W, const float* __restrict__ B,
               float* __restrict__ y) {
  __shared__ float zl[4][64][33];
  int lane = threadIdx.x & 63;
  int wid = threadIdx.x >> 6;
  int row = blockIdx.x * 256 + threadIdx.x;
  int rr = row < NN ? row : NN - 1;
  float* zrow = &zl[wid][lane][0];

  float acc[OUT];
  #pragma unroll
  for (int j = 0; j < OUT; ++j) acc[j] = B[j];

  #pragma unroll
  for (int c = 0; c < 4; ++c) {
    if (MODE == 0) {
      const float* base = (c < 2) ? in0 : in1;
      const float4* p = (const float4*)(base + (size_t)rr * 64 + (c & 1) * 32);
      #pragma unroll
      for (int q = 0; q < 8; ++q) {
        float4 v = p[q];
        zrow[4*q+0] = v.x; zrow[4*q+1] = v.y; zrow[4*q+2] = v.z; zrow[4*q+3] = v.w;
      }
    } else {
      const float4* p = (const float4*)(in0 + (size_t)rr * 128 + c * 32);
      #pragma unroll
      for (int q = 0; q < 8; ++q) {
        float4 v = p[q];
        int ci = c * 32 + 4 * q;
        float4 s = *(const float4*)(sc + ci);
        float4 b = *(const float4*)(bi + ci);
        zrow[4*q+0] = fmaxf(v.x * s.x + b.x, 0.f);
        zrow[4*q+1] = fmaxf(v.y * s.y + b.y, 0.f);
        zrow[4*q+2] = fmaxf(v.z * s.z + b.z, 0.f);
        zrow[4*q+3] = fmaxf(v.w * s.w + b.w, 0.f);
      }
    }
    const float* wseg = W + (size_t)c * 32 * OUT;
    #pragma unroll 1
    for (int k = 0; k < 32; ++k) {
      float zk = zrow[k];
      const float4* wr = (const float4*)(wseg + (size_t)k * OUT);
      #pragma unroll
      for (int q = 0; q < OUT / 4; ++q) {
        float4 w = wr[q];
        acc[4*q+0] += zk * w.x;
        acc[4*q+1] += zk * w.y;
        acc[4*q+2] += zk * w.z;
        acc[4*q+3] += zk * w.w;
      }
    }
  }
  if (row < NN) {
    float4* op = (float4*)(y + (size_t)row * OUT);
    #pragma unroll
    for (int q = 0; q < OUT / 4; ++q) {
      float4 v;
      v.x = acc[4*q+0]; v.y = acc[4*q+1]; v.z = acc[4*q+2]; v.w = acc[4*q+3];
      op[q] = v;
    }
  }
}

// ---------------------------------------------------------------------------
extern "C" void kernel_launch(void* const* d_in, const int* in_sizes, int n_in,
                              void* d_out, int out_size, void* d_ws, size_t ws_size,
                              hipStream_t stream) {
  const float* x     = (const float*)d_in[0];
  const int*   ei    = (const int*)d_in[1];
  const float* ea    = (const float*)d_in[2];
  const float* gh_w  = (const float*)d_in[3];
  const float* gh_b  = (const float*)d_in[4];
  const float* gv_w  = (const float*)d_in[5];
  const float* gv_b  = (const float*)d_in[6];
  const float* tpar  = (const float*)d_in[7];
  const float* p_w1  = (const float*)d_in[8];
  const float* p_b1  = (const float*)d_in[9];
  const float* p_w2  = (const float*)d_in[10];
  const float* p_b2  = (const float*)d_in[11];
  const float* h_w1  = (const float*)d_in[12];
  const float* h_b1  = (const float*)d_in[13];
  const float* h_g1  = (const float*)d_in[14];
  const float* h_bb1 = (const float*)d_in[15];
  const float* h_w2  = (const float*)d_in[16];
  const float* h_b2  = (const float*)d_in[17];
  const float* h_g2  = (const float*)d_in[18];
  const float* h_bb2 = (const float*)d_in[19];
  const float* h_w3  = (const float*)d_in[20];
  const float* h_b3  = (const float*)d_in[21];
  const float* h_g3  = (const float*)d_in[22];
  const float* h_bb3 = (const float*)d_in[23];
  const float* h_w4  = (const float*)d_in[24];
  const float* h_b4  = (const float*)d_in[25];
  const float* e_w1  = (const float*)d_in[26];
  const float* e_b1  = (const float*)d_in[27];
  const float* e_w2  = (const float*)d_in[28];
  const float* e_b2  = (const float*)d_in[29];

  float* h_out = (float*)d_out;
  float* v_out = (float*)d_out + (size_t)NN * 64;

  char* w = (char*)d_ws;
  // zeroed region: stats (4KB) + cnt + cursor
  float* stats = (float*)w;
  float* xsum = stats + 0,   *xsq = stats + 64;
  float* vsum = stats + 128, *vsq = stats + 192;
  float* ys1  = stats + 256, *yq1 = stats + 384;
  float* ys2  = stats + 512, *yq2 = stats + 640;
  float* ys3  = stats + 768, *yq3 = stats + 896;
  int* cnt    = (int*)(w + 4096);
  int* cursor = (int*)(w + 4096 + 200704);
  size_t zero_bytes = 4096 + 2 * 200704;

  char* p = w + zero_bytes;
  float* sb = (float*)p; p += 4096;
  float* sbx_s = sb,       *sbx_b = sb + 64;
  float* sbv_s = sb + 128, *sbv_b = sb + 192;
  float* sb1_s = sb + 256, *sb1_b = sb + 384;
  float* sb2_s = sb + 512, *sb2_b = sb + 640;
  float* sb3_s = sb + 768, *sb3_b = sb + 896;
  int* off    = (int*)p; p += 200704;
  int* sorted = (int*)p; p += (size_t)NE * 4;
  float* h    = (float*)p; p += (size_t)NN * 64 * 4;
  float* msg  = (float*)p; p += (size_t)NN * 64 * 4;
  float* y1   = (float*)p; p += (size_t)NN * 128 * 4;
  float* y2   = (float*)p; p += (size_t)NN * 128 * 4;
  float* m    = (float*)p; p += (size_t)NE * 64 * 4;

  hipMemsetAsync(d_ws, 0, zero_bytes, stream);

  // BN stats for x and edge_attr
  colstats<64><<<256, 256, 0, stream>>>(x, NN, xsum, xsq);
  colstats<64><<<1024, 256, 0, stream>>>(ea, NE, vsum, vsq);
  finalize_sb<<<1, 64, 0, stream>>>(xsum, xsq, 1.0f / NN, gh_w, gh_b, sbx_s, sbx_b, 64);
  finalize_sb<<<1, 64, 0, stream>>>(vsum, vsq, 1.0f / NE, gv_w, gv_b, sbv_s, sbv_b, 64);
  bn_relu64<<<3125, 256, 0, stream>>>(x, sbx_s, sbx_b, h);

  // CSR of edges by dst
  count_edges<<<3125, 256, 0, stream>>>(ei + NE, cnt);
  scan_offsets<<<1, 1024, 0, stream>>>(cnt, off);
  fill_sorted<<<3125, 256, 0, stream>>>(ei + NE, off, cursor, sorted);

  // message MLP: z = [h[dst] | h[src] | v]
  edge_mlp<false><<<3125, 256, 0, stream>>>(h, ei, ea, sbv_s, sbv_b,
                                            p_w1, p_b1, p_w2, p_b2, m, 1);
  // scatter-softmax aggregation
  node_softmax<<<12500, 256, 0, stream>>>(m, off, sorted, tpar, msg);

  // node MLP chain with BN between layers
  node_gemm<0, 128><<<196, 256, 0, stream>>>(h, msg, nullptr, nullptr, h_w1, h_b1, y1);
  colstats<128><<<512, 256, 0, stream>>>(y1, NN, ys1, yq1);
  finalize_sb<<<1, 128, 0, stream>>>(ys1, yq1, 1.0f / NN, h_g1, h_bb1, sb1_s, sb1_b, 128);

  node_gemm<1, 128><<<196, 256, 0, stream>>>(y1, nullptr, sb1_s, sb1_b, h_w2, h_b2, y2);
  colstats<128><<<512, 256, 0, stream>>>(y2, NN, ys2, yq2);
  finalize_sb<<<1, 128, 0, stream>>>(ys2, yq2, 1.0f / NN, h_g2, h_bb2, sb2_s, sb2_b, 128);

  node_gemm<1, 128><<<196, 256, 0, stream>>>(y2, nullptr, sb2_s, sb2_b, h_w3, h_b3, y1);
  colstats<128><<<512, 256, 0, stream>>>(y1, NN, ys3, yq3);
  finalize_sb<<<1, 128, 0, stream>>>(ys3, yq3, 1.0f / NN, h_g3, h_bb3, sb3_s, sb3_b, 128);

  node_gemm<1, 64><<<196, 256, 0, stream>>>(y1, nullptr, sb3_s, sb3_b, h_w4, h_b4, h_out);

  // edge output MLP: ev = relu([h_out[src] | h_out[dst] | v])
  edge_mlp<true><<<3125, 256, 0, stream>>>(h_out, ei, ea, sbv_s, sbv_b,
                                           e_w1, e_b1, e_w2, e_b2, v_out, 0);
}

// Round 2
// 1076.742 us; speedup vs baseline: 2.9574x; 2.9574x over previous
//
#include <hip/hip_runtime.h>
#include <math.h>

#define NN 50000
#define NE 800000

typedef __attribute__((ext_vector_type(8))) unsigned short us8;
typedef __attribute__((ext_vector_type(8))) __bf16 bf8;
typedef __attribute__((ext_vector_type(4))) float f4;

__device__ __forceinline__ unsigned short f2bf(float f) {
  unsigned int u = __float_as_uint(f);
  unsigned int r = u + 0x7FFFu + ((u >> 16) & 1u);
  return (unsigned short)(r >> 16);
}
__device__ __forceinline__ float bf2f(unsigned short h) {
  return __uint_as_float(((unsigned int)h) << 16);
}
__device__ __forceinline__ f4 mfma16(us8 a, us8 b, f4 c) {
  return __builtin_amdgcn_mfma_f32_16x16x32_bf16(
      __builtin_bit_cast(bf8, a), __builtin_bit_cast(bf8, b), c, 0, 0, 0);
}

// ---------------------------------------------------------------------------
// Column stats (sum, sumsq) for BN (training mode, biased var).
template<int C>
__global__ void colstats(const float* __restrict__ x, int rows,
                         float* __restrict__ sum, float* __restrict__ sq) {
  constexpr int RL = 256 / C;
  int c = threadIdx.x % C;
  int r0 = threadIdx.x / C;
  float s = 0.f, q = 0.f;
  for (int r = blockIdx.x * RL + r0; r < rows; r += gridDim.x * RL) {
    float v = x[(size_t)r * C + c];
    s += v; q += v * v;
  }
  __shared__ float ls[256], lq[256];
  ls[threadIdx.x] = s; lq[threadIdx.x] = q;
  __syncthreads();
  if (r0 == 0) {
    #pragma unroll
    for (int i = 1; i < RL; ++i) { s += ls[i * C + c]; q += lq[i * C + c]; }
    atomicAdd(&sum[c], s);
    atomicAdd(&sq[c], q);
  }
}

__global__ void finalize_sb(const float* __restrict__ sum, const float* __restrict__ sq,
                            float inv_rows,
                            const float* __restrict__ g, const float* __restrict__ b,
                            float* __restrict__ scale, float* __restrict__ bias, int C) {
  int c = threadIdx.x;
  if (c < C) {
    float mu = sum[c] * inv_rows;
    float var = sq[c] * inv_rows - mu * mu;
    float sc = g[c] * rsqrtf(var + 1e-5f);
    scale[c] = sc;
    bias[c] = b[c] - mu * sc;
  }
}

// h = relu(x*scale + bias), row width 64.
__global__ void bn_relu64(const float* __restrict__ x, const float* __restrict__ scale,
                          const float* __restrict__ bias, float* __restrict__ out) {
  int i = blockIdx.x * 256 + threadIdx.x;      // float4 index
  int c4 = (i & 15) * 4;
  float4 v = ((const float4*)x)[i];
  float4 s = *(const float4*)(scale + c4);
  float4 b = *(const float4*)(bias + c4);
  float4 r;
  r.x = fmaxf(v.x * s.x + b.x, 0.f);
  r.y = fmaxf(v.y * s.y + b.y, 0.f);
  r.z = fmaxf(v.z * s.z + b.z, 0.f);
  r.w = fmaxf(v.w * s.w + b.w, 0.f);
  ((float4*)out)[i] = r;
}

// ---------------------------------------------------------------------------
// weight transpose + bf16 convert: o[n*K+k] = bf16(w[k*N+n])
__global__ void wtrans(const float* __restrict__ w, unsigned short* __restrict__ o,
                       int K, int N) {
  int i = blockIdx.x * 256 + threadIdx.x;
  if (i >= K * N) return;
  int n = i / K, k = i - n * K;
  o[i] = f2bf(w[(size_t)k * N + n]);
}

// ---------------------------------------------------------------------------
// CSR build: count -> scan -> fill
__global__ void count_edges(const int* __restrict__ dst, int* __restrict__ cnt) {
  int e = blockIdx.x * 256 + threadIdx.x;
  atomicAdd(&cnt[dst[e]], 1);
}

__global__ void scan_offsets(const int* __restrict__ cnt, int* __restrict__ off) {
  __shared__ int buf[1024];
  __shared__ int carry;
  int tid = threadIdx.x;
  if (tid == 0) carry = 0;
  __syncthreads();
  for (int base = 0; base < NN; base += 1024) {
    int i = base + tid;
    int v = (i < NN) ? cnt[i] : 0;
    buf[tid] = v;
    __syncthreads();
    for (int d = 1; d < 1024; d <<= 1) {
      int t = (tid >= d) ? buf[tid - d] : 0;
      __syncthreads();
      buf[tid] += t;
      __syncthreads();
    }
    int incl = buf[tid];
    int cr = carry;
    __syncthreads();
    if (i < NN) off[i] = cr + incl - v;   // exclusive
    if (tid == 1023) carry = cr + incl;
    __syncthreads();
  }
  if (tid == 0) off[NN] = NE;
}

__global__ void fill_sorted(const int* __restrict__ dst, const int* __restrict__ off,
                            int* __restrict__ cursor, int* __restrict__ sorted) {
  int e = blockIdx.x * 256 + threadIdx.x;
  int n = dst[e];
  int p = atomicAdd(&cursor[n], 1);
  sorted[off[n] + p] = e;
}

// ---------------------------------------------------------------------------
// Fused 2-layer edge MLP on MFMA. Tile = 64 edges/block, 4 waves.
// Both layers computed transposed: D1^T = W1^T * Z^T, D2^T = W2^T * H^T.
// Z LDS [64][200] bf16, H LDS [64][136] bf16.
template<bool OUTBF>
__global__ __launch_bounds__(256) void edge_mlp_mfma(
    const float* __restrict__ hbase,
    const int* __restrict__ idxA, const int* __restrict__ idxB,
    const float* __restrict__ ea,
    const float* __restrict__ vsc, const float* __restrict__ vbi,
    const unsigned short* __restrict__ W1T, const float* __restrict__ B1,
    const unsigned short* __restrict__ W2T, const float* __restrict__ B2,
    void* __restrict__ outv) {
  __shared__ __align__(16) unsigned short Zl[64 * 200];
  __shared__ __align__(16) unsigned short Hl[64 * 136];
  const int t = threadIdx.x;
  const int w = t >> 6, l = t & 63, g = l >> 4, l15 = l & 15;
  const size_t e0 = (size_t)blockIdx.x * 64;

  // ---- stage Z: 64 edges x (h[A] | h[B] | bnrelu(ea)) as bf16
  {
    int r = t >> 2, q = t & 3;
    size_t e = e0 + r;
    int na = idxA[e], nb = idxB[e];
    const float4* pa = (const float4*)(hbase + (size_t)na * 64 + q * 16);
    const float4* pb = (const float4*)(hbase + (size_t)nb * 64 + q * 16);
    const float4* pv = (const float4*)(ea + e * 64 + q * 16);
    unsigned short* zr = &Zl[r * 200];
    unsigned short tmp[16];
    #pragma unroll
    for (int i = 0; i < 4; ++i) {
      float4 v = pa[i];
      tmp[4*i+0] = f2bf(fmaxf(v.x, 0.f)); tmp[4*i+1] = f2bf(fmaxf(v.y, 0.f));
      tmp[4*i+2] = f2bf(fmaxf(v.z, 0.f)); tmp[4*i+3] = f2bf(fmaxf(v.w, 0.f));
    }
    *(uint4*)&zr[q * 16] = *(uint4*)tmp;
    *(uint4*)&zr[q * 16 + 8] = *(uint4*)(tmp + 8);
    #pragma unroll
    for (int i = 0; i < 4; ++i) {
      float4 v = pb[i];
      tmp[4*i+0] = f2bf(fmaxf(v.x, 0.f)); tmp[4*i+1] = f2bf(fmaxf(v.y, 0.f));
      tmp[4*i+2] = f2bf(fmaxf(v.z, 0.f)); tmp[4*i+3] = f2bf(fmaxf(v.w, 0.f));
    }
    *(uint4*)&zr[64 + q * 16] = *(uint4*)tmp;
    *(uint4*)&zr[64 + q * 16 + 8] = *(uint4*)(tmp + 8);
    #pragma unroll
    for (int i = 0; i < 4; ++i) {
      float4 v = pv[i];
      float4 s = ((const float4*)(vsc + q * 16))[i];
      float4 b = ((const float4*)(vbi + q * 16))[i];
      tmp[4*i+0] = f2bf(fmaxf(v.x * s.x + b.x, 0.f));
      tmp[4*i+1] = f2bf(fmaxf(v.y * s.y + b.y, 0.f));
      tmp[4*i+2] = f2bf(fmaxf(v.z * s.z + b.z, 0.f));
      tmp[4*i+3] = f2bf(fmaxf(v.w * s.w + b.w, 0.f));
    }
    *(uint4*)&zr[128 + q * 16] = *(uint4*)tmp;
    *(uint4*)&zr[128 + q * 16 + 8] = *(uint4*)(tmp + 8);
  }

  // ---- preload W1^T fragments (wave w owns f1 in [32w, 32w+32)) + biases
  us8 a1[2][6];
  #pragma unroll
  for (int mm = 0; mm < 2; ++mm)
    #pragma unroll
    for (int kc = 0; kc < 6; ++kc)
      a1[mm][kc] = *(const us8*)(W1T + (size_t)(16 * (2 * w + mm) + l15) * 192
                                 + kc * 32 + g * 8);
  float b1v[2][4];
  #pragma unroll
  for (int mm = 0; mm < 2; ++mm)
    #pragma unroll
    for (int r = 0; r < 4; ++r)
      b1v[mm][r] = B1[16 * (2 * w + mm) + 4 * g + r];
  float b2v[4][4];
  #pragma unroll
  for (int mb = 0; mb < 4; ++mb)
    #pragma unroll
    for (int r = 0; r < 4; ++r)
      b2v[mb][r] = B2[16 * mb + 4 * g + r];

  __syncthreads();

  // ---- layer 1: D1^T[f1][e] = sum_k W1T[f1][k] * Z[e][k]
  f4 c1[2][4];
  #pragma unroll
  for (int mm = 0; mm < 2; ++mm)
    #pragma unroll
    for (int nb = 0; nb < 4; ++nb)
      c1[mm][nb] = (f4){b1v[mm][0], b1v[mm][1], b1v[mm][2], b1v[mm][3]};
  #pragma unroll
  for (int kc = 0; kc < 6; ++kc) {
    us8 bz[4];
    #pragma unroll
    for (int nb = 0; nb < 4; ++nb)
      bz[nb] = *(const us8*)&Zl[(16 * nb + l15) * 200 + kc * 32 + g * 8];
    #pragma unroll
    for (int mm = 0; mm < 2; ++mm)
      #pragma unroll
      for (int nb = 0; nb < 4; ++nb)
        c1[mm][nb] = mfma16(a1[mm][kc], bz[nb], c1[mm][nb]);
  }

  // ---- relu -> bf16 -> H LDS (lane holds 4 consecutive f1 at fixed edge)
  #pragma unroll
  for (int mm = 0; mm < 2; ++mm)
    #pragma unroll
    for (int nb = 0; nb < 4; ++nb) {
      f4 v = c1[mm][nb];
      unsigned int u0 = (unsigned int)f2bf(fmaxf(v[0], 0.f))
                      | ((unsigned int)f2bf(fmaxf(v[1], 0.f)) << 16);
      unsigned int u1 = (unsigned int)f2bf(fmaxf(v[2], 0.f))
                      | ((unsigned int)f2bf(fmaxf(v[3], 0.f)) << 16);
      int er = l15 + 16 * nb;
      int f1 = 16 * (2 * w + mm) + 4 * g;
      *(uint2*)&Hl[er * 136 + f1] = (uint2){u0, u1};
    }

  __syncthreads();

  // ---- layer 2: D2^T[f][e] = sum_f1 W2T[f][f1] * H[e][f1]; wave w -> e block w
  f4 c2[4];
  #pragma unroll
  for (int mb = 0; mb < 4; ++mb)
    c2[mb] = (f4){b2v[mb][0], b2v[mb][1], b2v[mb][2], b2v[mb][3]};
  #pragma unroll
  for (int kc = 0; kc < 4; ++kc) {
    us8 bh = *(const us8*)&Hl[(l15 + 16 * w) * 136 + kc * 32 + g * 8];
    #pragma unroll
    for (int mb = 0; mb < 4; ++mb) {
      us8 a2 = *(const us8*)(W2T + (size_t)(16 * mb + l15) * 128 + kc * 32 + g * 8);
      c2[mb] = mfma16(a2, bh, c2[mb]);
    }
  }

  // ---- store: lane holds 4 consecutive f at edge (l15 + 16w)
  size_t e = e0 + l15 + 16 * w;
  #pragma unroll
  for (int mb = 0; mb < 4; ++mb) {
    int f0 = 16 * mb + 4 * g;
    if (OUTBF) {
      unsigned int u0 = (unsigned int)f2bf(c2[mb][0]) | ((unsigned int)f2bf(c2[mb][1]) << 16);
      unsigned int u1 = (unsigned int)f2bf(c2[mb][2]) | ((unsigned int)f2bf(c2[mb][3]) << 16);
      *(uint2*)((unsigned short*)outv + e * 64 + f0) = (uint2){u0, u1};
    } else {
      *(float4*)((float*)outv + e * 64 + f0) =
          (float4){c2[mb][0], c2[mb][1], c2[mb][2], c2[mb][3]};
    }
  }
}

// ---------------------------------------------------------------------------
// Node GEMM on MFMA: y[row][0:OUTW] = U[row][0:128] @ W + B, transposed compute.
// MODE 0: U = [in0_row(64) | in1_row(64)] raw. MODE 1: U = relu(in0*sc+bi).
template<int MODE, int OUTW>
__global__ __launch_bounds__(256) void node_mfma(
    const float* __restrict__ in0, const float* __restrict__ in1,
    const float* __restrict__ sc, const float* __restrict__ bi,
    const unsigned short* __restrict__ WT, const float* __restrict__ B,
    float* __restrict__ y) {
  __shared__ __align__(16) unsigned short Ul[64 * 136];
  const int t = threadIdx.x;
  const int w = t >> 6, l = t & 63, g = l >> 4, l15 = l & 15;
  const int r0 = blockIdx.x * 64;
  constexpr int NMB = OUTW / 64;   // m-blocks per wave

  // ---- stage U (64 rows x 128 bf16)
  {
    int r = t >> 2, q = t & 3;
    int row = r0 + r;
    int rr = row < NN ? row : NN - 1;
    unsigned short tmp[32];
    if (MODE == 0) {
      const float4* p = (q < 2) ? (const float4*)(in0 + (size_t)rr * 64 + q * 32)
                                : (const float4*)(in1 + (size_t)rr * 64 + (q - 2) * 32);
      #pragma unroll
      for (int i = 0; i < 8; ++i) {
        float4 v = p[i];
        tmp[4*i+0] = f2bf(v.x); tmp[4*i+1] = f2bf(v.y);
        tmp[4*i+2] = f2bf(v.z); tmp[4*i+3] = f2bf(v.w);
      }
    } else {
      const float4* p = (const float4*)(in0 + (size_t)rr * 128 + q * 32);
      #pragma unroll
      for (int i = 0; i < 8; ++i) {
        float4 v = p[i];
        float4 s = ((const float4*)(sc + q * 32))[i];
        float4 b = ((const float4*)(bi + q * 32))[i];
        tmp[4*i+0] = f2bf(fmaxf(v.x * s.x + b.x, 0.f));
        tmp[4*i+1] = f2bf(fmaxf(v.y * s.y + b.y, 0.f));
        tmp[4*i+2] = f2bf(fmaxf(v.z * s.z + b.z, 0.f));
        tmp[4*i+3] = f2bf(fmaxf(v.w * s.w + b.w, 0.f));
      }
    }
    unsigned short* ur = &Ul[r * 136 + q * 32];
    #pragma unroll
    for (int i = 0; i < 4; ++i)
      *(uint4*)&ur[i * 8] = *(uint4*)(tmp + i * 8);
  }

  float bv[NMB][4];
  #pragma unroll
  for (int mm = 0; mm < NMB; ++mm)
    #pragma unroll
    for (int r = 0; r < 4; ++r)
      bv[mm][r] = B[16 * (NMB * w + mm) + 4 * g + r];

  __syncthreads();

  f4 c[NMB][4];
  #pragma unroll
  for (int mm = 0; mm < NMB; ++mm)
    #pragma unroll
    for (int nb = 0; nb < 4; ++nb)
      c[mm][nb] = (f4){bv[mm][0], bv[mm][1], bv[mm][2], bv[mm][3]};

  #pragma unroll
  for (int kc = 0; kc < 4; ++kc) {
    us8 bu[4];
    #pragma unroll
    for (int nb = 0; nb < 4; ++nb)
      bu[nb] = *(const us8*)&Ul[(16 * nb + l15) * 136 + kc * 32 + g * 8];
    #pragma unroll
    for (int mm = 0; mm < NMB; ++mm) {
      us8 a = *(const us8*)(WT + (size_t)(16 * (NMB * w + mm) + l15) * 128
                            + kc * 32 + g * 8);
      #pragma unroll
      for (int nb = 0; nb < 4; ++nb)
        c[mm][nb] = mfma16(a, bu[nb], c[mm][nb]);
    }
  }

  #pragma unroll
  for (int mm = 0; mm < NMB; ++mm)
    #pragma unroll
    for (int nb = 0; nb < 4; ++nb) {
      int row = r0 + l15 + 16 * nb;
      if (row < NN) {
        int f0 = 16 * (NMB * w + mm) + 4 * g;
        *(float4*)&y[(size_t)row * OUTW + f0] =
            (float4){c[mm][nb][0], c[mm][nb][1], c[mm][nb][2], c[mm][nb][3]};
      }
    }
}

// ---------------------------------------------------------------------------
// Per-node online scatter-softmax + weighted aggregation (m in bf16).
__global__ void node_softmax(const unsigned short* __restrict__ m,
                             const int* __restrict__ off,
                             const int* __restrict__ sorted,
                             const float* __restrict__ tptr,
                             float* __restrict__ msg) {
  int gw = (blockIdx.x * 256 + threadIdx.x) >> 6;
  int lane = threadIdx.x & 63;
  if (gw >= NN) return;
  float t = tptr[0];
  int beg = off[gw], end = off[gw + 1];
  float M = -1e30f, S = 0.f, Wn = 0.f;
  for (int i = beg; i < end; ++i) {
    int e = sorted[i];
    float mv = bf2f(m[(size_t)e * 64 + lane]);
    float s = mv * t;
    float Mn = fmaxf(M, s);
    float c = __expf(M - Mn);
    float p = __expf(s - Mn);
    S = S * c + p;
    Wn = Wn * c + mv * p;
    M = Mn;
  }
  msg[(size_t)gw * 64 + lane] = (end > beg) ? (Wn / S) : 0.f;
}

// ---------------------------------------------------------------------------
extern "C" void kernel_launch(void* const* d_in, const int* in_sizes, int n_in,
                              void* d_out, int out_size, void* d_ws, size_t ws_size,
                              hipStream_t stream) {
  const float* x     = (const float*)d_in[0];
  const int*   ei    = (const int*)d_in[1];
  const float* ea    = (const float*)d_in[2];
  const float* gh_w  = (const float*)d_in[3];
  const float* gh_b  = (const float*)d_in[4];
  const float* gv_w  = (const float*)d_in[5];
  const float* gv_b  = (const float*)d_in[6];
  const float* tpar  = (const float*)d_in[7];
  const float* p_w1  = (const float*)d_in[8];
  const float* p_b1  = (const float*)d_in[9];
  const float* p_w2  = (const float*)d_in[10];
  const float* p_b2  = (const float*)d_in[11];
  const float* h_w1  = (const float*)d_in[12];
  const float* h_b1  = (const float*)d_in[13];
  const float* h_g1  = (const float*)d_in[14];
  const float* h_bb1 = (const float*)d_in[15];
  const float* h_w2  = (const float*)d_in[16];
  const float* h_b2  = (const float*)d_in[17];
  const float* h_g2  = (const float*)d_in[18];
  const float* h_bb2 = (const float*)d_in[19];
  const float* h_w3  = (const float*)d_in[20];
  const float* h_b3  = (const float*)d_in[21];
  const float* h_g3  = (const float*)d_in[22];
  const float* h_bb3 = (const float*)d_in[23];
  const float* h_w4  = (const float*)d_in[24];
  const float* h_b4  = (const float*)d_in[25];
  const float* e_w1  = (const float*)d_in[26];
  const float* e_b1  = (const float*)d_in[27];
  const float* e_w2  = (const float*)d_in[28];
  const float* e_b2  = (const float*)d_in[29];

  float* h_out = (float*)d_out;
  float* v_out = (float*)d_out + (size_t)NN * 64;

  char* w = (char*)d_ws;
  // zeroed region: stats (4KB) + cnt + cursor
  float* stats = (float*)w;
  float* xsum = stats + 0,   *xsq = stats + 64;
  float* vsum = stats + 128, *vsq = stats + 192;
  float* ys1  = stats + 256, *yq1 = stats + 384;
  float* ys2  = stats + 512, *yq2 = stats + 640;
  float* ys3  = stats + 768, *yq3 = stats + 896;
  int* cnt    = (int*)(w + 4096);
  int* cursor = (int*)(w + 4096 + 200704);
  size_t zero_bytes = 4096 + 2 * 200704;

  char* p = w + zero_bytes;
  float* sb = (float*)p; p += 4096;
  float* sbx_s = sb,       *sbx_b = sb + 64;
  float* sbv_s = sb + 128, *sbv_b = sb + 192;
  float* sb1_s = sb + 256, *sb1_b = sb + 384;
  float* sb2_s = sb + 512, *sb2_b = sb + 640;
  float* sb3_s = sb + 768, *sb3_b = sb + 896;
  int* off    = (int*)p; p += 200704;
  int* sorted = (int*)p; p += (size_t)NE * 4;
  float* h    = (float*)p; p += (size_t)NN * 64 * 4;
  float* msg  = (float*)p; p += (size_t)NN * 64 * 4;
  float* y1   = (float*)p; p += (size_t)NN * 128 * 4;
  float* y2   = (float*)p; p += (size_t)NN * 128 * 4;
  unsigned short* m_bf = (unsigned short*)p; p += (size_t)NE * 64 * 2;
  unsigned short* p_w1t = (unsigned short*)p; p += 192 * 128 * 2;
  unsigned short* p_w2t = (unsigned short*)p; p += 128 * 64 * 2;
  unsigned short* e_w1t = (unsigned short*)p; p += 192 * 128 * 2;
  unsigned short* e_w2t = (unsigned short*)p; p += 128 * 64 * 2;
  unsigned short* h_w1t = (unsigned short*)p; p += 128 * 128 * 2;
  unsigned short* h_w2t = (unsigned short*)p; p += 128 * 128 * 2;
  unsigned short* h_w3t = (unsigned short*)p; p += 128 * 128 * 2;
  unsigned short* h_w4t = (unsigned short*)p; p += 128 * 64 * 2;

  hipMemsetAsync(d_ws, 0, zero_bytes, stream);

  // weight transpose+convert (tiny)
  wtrans<<<96, 256, 0, stream>>>(p_w1, p_w1t, 192, 128);
  wtrans<<<32, 256, 0, stream>>>(p_w2, p_w2t, 128, 64);
  wtrans<<<96, 256, 0, stream>>>(e_w1, e_w1t, 192, 128);
  wtrans<<<32, 256, 0, stream>>>(e_w2, e_w2t, 128, 64);
  wtrans<<<64, 256, 0, stream>>>(h_w1, h_w1t, 128, 128);
  wtrans<<<64, 256, 0, stream>>>(h_w2, h_w2t, 128, 128);
  wtrans<<<64, 256, 0, stream>>>(h_w3, h_w3t, 128, 128);
  wtrans<<<32, 256, 0, stream>>>(h_w4, h_w4t, 128, 64);

  // BN stats for x and edge_attr
  colstats<64><<<256, 256, 0, stream>>>(x, NN, xsum, xsq);
  colstats<64><<<1024, 256, 0, stream>>>(ea, NE, vsum, vsq);
  finalize_sb<<<1, 64, 0, stream>>>(xsum, xsq, 1.0f / NN, gh_w, gh_b, sbx_s, sbx_b, 64);
  finalize_sb<<<1, 64, 0, stream>>>(vsum, vsq, 1.0f / NE, gv_w, gv_b, sbv_s, sbv_b, 64);
  bn_relu64<<<3125, 256, 0, stream>>>(x, sbx_s, sbx_b, h);

  // CSR of edges by dst
  count_edges<<<3125, 256, 0, stream>>>(ei + NE, cnt);
  scan_offsets<<<1, 1024, 0, stream>>>(cnt, off);
  fill_sorted<<<3125, 256, 0, stream>>>(ei + NE, off, cursor, sorted);

  // message MLP: z = [h[dst] | h[src] | v]  -> m (bf16)
  edge_mlp_mfma<true><<<12500, 256, 0, stream>>>(
      h, ei + NE, ei, ea, sbv_s, sbv_b, p_w1t, p_b1, p_w2t, p_b2, (void*)m_bf);

  // scatter-softmax aggregation
  node_softmax<<<12500, 256, 0, stream>>>(m_bf, off, sorted, tpar, msg);

  // node MLP chain with BN between layers
  node_mfma<0, 128><<<782, 256, 0, stream>>>(h, msg, nullptr, nullptr, h_w1t, h_b1, y1);
  colstats<128><<<512, 256, 0, stream>>>(y1, NN, ys1, yq1);
  finalize_sb<<<1, 128, 0, stream>>>(ys1, yq1, 1.0f / NN, h_g1, h_bb1, sb1_s, sb1_b, 128);

  node_mfma<1, 128><<<782, 256, 0, stream>>>(y1, nullptr, sb1_s, sb1_b, h_w2t, h_b2, y2);
  colstats<128><<<512, 256, 0, stream>>>(y2, NN, ys2, yq2);
  finalize_sb<<<1, 128, 0, stream>>>(ys2, yq2, 1.0f / NN, h_g2, h_bb2, sb2_s, sb2_b, 128);

  node_mfma<1, 128><<<782, 256, 0, stream>>>(y2, nullptr, sb2_s, sb2_b, h_w3t, h_b3, y1);
  colstats<128><<<512, 256, 0, stream>>>(y1, NN, ys3, yq3);
  finalize_sb<<<1, 128, 0, stream>>>(ys3, yq3, 1.0f / NN, h_g3, h_bb3, sb3_s, sb3_b, 128);

  node_mfma<1, 64><<<782, 256, 0, stream>>>(y1, nullptr, sb3_s, sb3_b, h_w4t, h_b4, h_out);

  // edge output MLP: ev = relu([h_out[src] | h_out[dst] | v]) -> v_out (f32)
  edge_mlp_mfma<false><<<12500, 256, 0, stream>>>(
      h_out, ei, ei + NE, ea, sbv_s, sbv_b, e_w1t, e_b1, e_w2t, e_b2, (void*)v_out);
}

// Round 3
// 1044.455 us; speedup vs baseline: 3.0488x; 1.0309x over previous
//
#include <hip/hip_runtime.h>
#include <math.h>

#define NN 50000
#define NE 800000

typedef __attribute__((ext_vector_type(8))) unsigned short us8;
typedef __attribute__((ext_vector_type(8))) __bf16 bf8;
typedef __attribute__((ext_vector_type(4))) float f4;

__device__ __forceinline__ unsigned short f2bf(float f) {
  unsigned int u = __float_as_uint(f);
  unsigned int r = u + 0x7FFFu + ((u >> 16) & 1u);
  return (unsigned short)(r >> 16);
}
__device__ __forceinline__ float bf2f(unsigned short h) {
  return __uint_as_float(((unsigned int)h) << 16);
}
__device__ __forceinline__ f4 mfma16(us8 a, us8 b, f4 c) {
  return __builtin_amdgcn_mfma_f32_16x16x32_bf16(
      __builtin_bit_cast(bf8, a), __builtin_bit_cast(bf8, b), c, 0, 0, 0);
}
__device__ __forceinline__ uint2 pack4(float a, float b, float c, float d) {
  uint2 r;
  r.x = (unsigned)f2bf(a) | ((unsigned)f2bf(b) << 16);
  r.y = (unsigned)f2bf(c) | ((unsigned)f2bf(d) << 16);
  return r;
}

// ---------------------------------------------------------------------------
// Column stats (sum, sumsq) for BN (training mode, biased var). f32 input.
template<int C>
__global__ void colstats(const float* __restrict__ x, int rows,
                         float* __restrict__ sum, float* __restrict__ sq) {
  constexpr int RL = 256 / C;
  int c = threadIdx.x % C;
  int r0 = threadIdx.x / C;
  float s = 0.f, q = 0.f;
  for (int r = blockIdx.x * RL + r0; r < rows; r += gridDim.x * RL) {
    float v = x[(size_t)r * C + c];
    s += v; q += v * v;
  }
  __shared__ float ls[256], lq[256];
  ls[threadIdx.x] = s; lq[threadIdx.x] = q;
  __syncthreads();
  if (r0 == 0) {
    #pragma unroll
    for (int i = 1; i < RL; ++i) { s += ls[i * C + c]; q += lq[i * C + c]; }
    atomicAdd(&sum[c], s);
    atomicAdd(&sq[c], q);
  }
}

// bf16 input variant
template<int C>
__global__ void colstats_bf(const unsigned short* __restrict__ x, int rows,
                            float* __restrict__ sum, float* __restrict__ sq) {
  constexpr int RL = 256 / C;
  int c = threadIdx.x % C;
  int r0 = threadIdx.x / C;
  float s = 0.f, q = 0.f;
  for (int r = blockIdx.x * RL + r0; r < rows; r += gridDim.x * RL) {
    float v = bf2f(x[(size_t)r * C + c]);
    s += v; q += v * v;
  }
  __shared__ float ls[256], lq[256];
  ls[threadIdx.x] = s; lq[threadIdx.x] = q;
  __syncthreads();
  if (r0 == 0) {
    #pragma unroll
    for (int i = 1; i < RL; ++i) { s += ls[i * C + c]; q += lq[i * C + c]; }
    atomicAdd(&sum[c], s);
    atomicAdd(&sq[c], q);
  }
}

__global__ void finalize_sb(const float* __restrict__ sum, const float* __restrict__ sq,
                            float inv_rows,
                            const float* __restrict__ g, const float* __restrict__ b,
                            float* __restrict__ scale, float* __restrict__ bias, int C) {
  int c = threadIdx.x;
  if (c < C) {
    float mu = sum[c] * inv_rows;
    float var = sq[c] * inv_rows - mu * mu;
    float sc = g[c] * rsqrtf(var + 1e-5f);
    scale[c] = sc;
    bias[c] = b[c] - mu * sc;
  }
}

// h = relu(x*scale + bias), row width 64, f32 out (for node h).
__global__ void bn_relu64(const float* __restrict__ x, const float* __restrict__ scale,
                          const float* __restrict__ bias, float* __restrict__ out) {
  int i = blockIdx.x * 256 + threadIdx.x;      // float4 index
  int c4 = (i & 15) * 4;
  float4 v = ((const float4*)x)[i];
  float4 s = *(const float4*)(scale + c4);
  float4 b = *(const float4*)(bias + c4);
  float4 r;
  r.x = fmaxf(v.x * s.x + b.x, 0.f);
  r.y = fmaxf(v.y * s.y + b.y, 0.f);
  r.z = fmaxf(v.z * s.z + b.z, 0.f);
  r.w = fmaxf(v.w * s.w + b.w, 0.f);
  ((float4*)out)[i] = r;
}

// vbf = bf16(relu(ea*scale+bias)), row width 64. 8 elems/thread.
__global__ void bn_relu_bf(const float* __restrict__ x, const float* __restrict__ scale,
                           const float* __restrict__ bias, unsigned short* __restrict__ out) {
  size_t i = (size_t)blockIdx.x * 256 + threadIdx.x;   // 8-elem chunk index
  int c8 = ((int)i & 7) * 8;
  const float4* px = (const float4*)x + 2 * i;
  float4 a = px[0], b = px[1];
  float4 s0 = *(const float4*)(scale + c8), s1 = *(const float4*)(scale + c8 + 4);
  float4 b0 = *(const float4*)(bias + c8),  b1 = *(const float4*)(bias + c8 + 4);
  unsigned short tmp[8];
  tmp[0] = f2bf(fmaxf(a.x * s0.x + b0.x, 0.f));
  tmp[1] = f2bf(fmaxf(a.y * s0.y + b0.y, 0.f));
  tmp[2] = f2bf(fmaxf(a.z * s0.z + b0.z, 0.f));
  tmp[3] = f2bf(fmaxf(a.w * s0.w + b0.w, 0.f));
  tmp[4] = f2bf(fmaxf(b.x * s1.x + b1.x, 0.f));
  tmp[5] = f2bf(fmaxf(b.y * s1.y + b1.y, 0.f));
  tmp[6] = f2bf(fmaxf(b.z * s1.z + b1.z, 0.f));
  tmp[7] = f2bf(fmaxf(b.w * s1.w + b1.w, 0.f));
  *(uint4*)(out + i * 8) = *(uint4*)tmp;
}

// ---------------------------------------------------------------------------
// weight transpose + bf16 convert: o[n*K+k] = bf16(w[k*N+n])
__global__ void wtrans(const float* __restrict__ w, unsigned short* __restrict__ o,
                       int K, int N) {
  int i = blockIdx.x * 256 + threadIdx.x;
  if (i >= K * N) return;
  int n = i / K, k = i - n * K;
  o[i] = f2bf(w[(size_t)k * N + n]);
}

// o[f*64+k] = bf16(w[(k + (f>=128)*64)*128 + (f&127)]), f in [0,256), k in [0,64)
__global__ void wtrans_pair(const float* __restrict__ w, unsigned short* __restrict__ o) {
  int i = blockIdx.x * 256 + threadIdx.x;   // 16384 total
  int f = i >> 6, k = i & 63;
  int srcrow = k + ((f >> 7) << 6);
  o[i] = f2bf(w[(size_t)srcrow * 128 + (f & 127)]);
}

// ---------------------------------------------------------------------------
// CSR build: count -> scan -> perm
__global__ void count_edges(const int* __restrict__ dst, int* __restrict__ cnt) {
  int e = blockIdx.x * 256 + threadIdx.x;
  atomicAdd(&cnt[dst[e]], 1);
}

// single block, 1024 threads, 2-pass per-thread + one block scan
__global__ void scan_offsets(const int* __restrict__ cnt, int* __restrict__ off) {
  __shared__ int ps[1024];
  const int NPT = (NN + 1023) / 1024;   // 49
  int t = threadIdx.x;
  int base = t * NPT;
  int end = base + NPT; if (end > NN) end = NN;
  int s = 0;
  for (int i = base; i < end; ++i) s += cnt[i];
  ps[t] = s;
  __syncthreads();
  for (int d = 1; d < 1024; d <<= 1) {
    int v = (t >= d) ? ps[t - d] : 0;
    __syncthreads();
    ps[t] += v;
    __syncthreads();
  }
  int pre = t ? ps[t - 1] : 0;
  for (int i = base; i < end; ++i) { off[i] = pre; pre += cnt[i]; }
  if (t == 1023) off[NN] = NE;
}

__global__ void fill_perm(const int* __restrict__ dst, const int* __restrict__ off,
                          int* __restrict__ cursor, int* __restrict__ perm) {
  int e = blockIdx.x * 256 + threadIdx.x;
  int n = dst[e];
  int p = atomicAdd(&cursor[n], 1);
  perm[e] = off[n] + p;
}

// ---------------------------------------------------------------------------
// PAB = bf16( relu(in) @ WT^T ) : in [NN][64] f32, WT [256][64] bf16 (row f, col k),
// out [NN][256] bf16. 64 rows/block, 4 waves; wave w owns f in [64w, 64w+64).
__global__ __launch_bounds__(256) void pab_gemm(
    const float* __restrict__ in, const unsigned short* __restrict__ WT,
    unsigned short* __restrict__ out) {
  __shared__ __align__(16) unsigned short Ul[64 * 72];
  const int t = threadIdx.x;
  const int w = t >> 6, l = t & 63, g = l >> 4, l15 = l & 15;
  const int r0 = blockIdx.x * 64;

  {
    #pragma unroll
    for (int it = 0; it < 2; ++it) {
      int idx = it * 256 + t;            // 0..511
      int r = idx >> 3, q = idx & 7;     // 8B chunks of 64-col row
      int row = r0 + r; int rr = row < NN ? row : NN - 1;
      float4 v = *(const float4*)(in + (size_t)rr * 64 + q * 8);
      float4 v2 = *(const float4*)(in + (size_t)rr * 64 + q * 8 + 4);
      unsigned short tmp[8];
      tmp[0] = f2bf(fmaxf(v.x, 0.f));  tmp[1] = f2bf(fmaxf(v.y, 0.f));
      tmp[2] = f2bf(fmaxf(v.z, 0.f));  tmp[3] = f2bf(fmaxf(v.w, 0.f));
      tmp[4] = f2bf(fmaxf(v2.x, 0.f)); tmp[5] = f2bf(fmaxf(v2.y, 0.f));
      tmp[6] = f2bf(fmaxf(v2.z, 0.f)); tmp[7] = f2bf(fmaxf(v2.w, 0.f));
      *(uint4*)&Ul[r * 72 + q * 8] = *(uint4*)tmp;
    }
  }
  us8 a[4][2];
  #pragma unroll
  for (int mm = 0; mm < 4; ++mm)
    #pragma unroll
    for (int kc = 0; kc < 2; ++kc)
      a[mm][kc] = *(const us8*)(WT + (size_t)(64 * w + 16 * mm + l15) * 64 + kc * 32 + g * 8);
  __syncthreads();

  f4 c[4][4];
  #pragma unroll
  for (int mm = 0; mm < 4; ++mm)
    #pragma unroll
    for (int nb = 0; nb < 4; ++nb)
      c[mm][nb] = (f4){0.f, 0.f, 0.f, 0.f};
  #pragma unroll
  for (int kc = 0; kc < 2; ++kc) {
    us8 bz[4];
    #pragma unroll
    for (int nb = 0; nb < 4; ++nb)
      bz[nb] = *(const us8*)&Ul[(16 * nb + l15) * 72 + kc * 32 + g * 8];
    #pragma unroll
    for (int mm = 0; mm < 4; ++mm)
      #pragma unroll
      for (int nb = 0; nb < 4; ++nb)
        c[mm][nb] = mfma16(a[mm][kc], bz[nb], c[mm][nb]);
  }
  #pragma unroll
  for (int mm = 0; mm < 4; ++mm)
    #pragma unroll
    for (int nb = 0; nb < 4; ++nb) {
      int row = r0 + 16 * nb + l15;
      if (row < NN) {
        int f0 = 64 * w + 16 * mm + 4 * g;
        *(uint2*)(out + (size_t)row * 256 + f0) =
            pack4(c[mm][nb][0], c[mm][nb][1], c[mm][nb][2], c[mm][nb][3]);
      }
    }
}

// ---------------------------------------------------------------------------
// Edge MLP with node-side factorization:
//   hidden = relu( PAB[idx0[e]][f] + PAB[idx1[e]][128+f] + (v @ W1c)[e][f] + B1[f] )
//   out    = hidden @ W2 + B2
// 64 edges/block, 4 waves.
template<bool PERM_OUT>
__global__ __launch_bounds__(256) void edge_mlp2(
    const unsigned short* __restrict__ vbf,
    const unsigned short* __restrict__ PAB,
    const int* __restrict__ idx0, const int* __restrict__ idx1,
    const unsigned short* __restrict__ W1cT, const float* __restrict__ B1,
    const unsigned short* __restrict__ W2T, const float* __restrict__ B2,
    const int* __restrict__ perm, void* __restrict__ outv) {
  __shared__ __align__(16) unsigned short Vl[64 * 72];
  __shared__ __align__(16) unsigned short Hl[64 * 136];
  const int t = threadIdx.x;
  const int w = t >> 6, l = t & 63, g = l >> 4, l15 = l & 15;
  const size_t e0 = (size_t)blockIdx.x * 64;

  // stage V tile (straight bf16 copy, coalesced)
  #pragma unroll
  for (int it = 0; it < 2; ++it) {
    int idx = it * 256 + t;
    int r = idx >> 3, q = idx & 7;
    *(uint4*)&Vl[r * 72 + q * 8] = *(const uint4*)&vbf[(e0 + r) * 64 + q * 8];
  }

  // early-issue PAB gathers (consumed after MFMA)
  uint2 ga[2][2][4];   // [table][mm][nb]
  const int f1b = 32 * w + 4 * g;
  #pragma unroll
  for (int nb = 0; nb < 4; ++nb) {
    size_t e = e0 + 16 * nb + l15;
    int n0 = idx0[e], n1 = idx1[e];
    const unsigned short* r0p = PAB + (size_t)n0 * 256;
    const unsigned short* r1p = PAB + (size_t)n1 * 256 + 128;
    #pragma unroll
    for (int mm = 0; mm < 2; ++mm) {
      ga[0][mm][nb] = *(const uint2*)(r0p + f1b + 16 * mm);
      ga[1][mm][nb] = *(const uint2*)(r1p + f1b + 16 * mm);
    }
  }

  // W1c fragments (wave w owns f1 in [32w, 32w+32))
  us8 a1[2][2];
  #pragma unroll
  for (int mm = 0; mm < 2; ++mm)
    #pragma unroll
    for (int kc = 0; kc < 2; ++kc)
      a1[mm][kc] = *(const us8*)(W1cT + (size_t)(32 * w + 16 * mm + l15) * 64
                                 + kc * 32 + g * 8);
  __syncthreads();

  // EV^T = W1c^T * V^T
  f4 c1[2][4];
  #pragma unroll
  for (int mm = 0; mm < 2; ++mm)
    #pragma unroll
    for (int nb = 0; nb < 4; ++nb)
      c1[mm][nb] = (f4){0.f, 0.f, 0.f, 0.f};
  #pragma unroll
  for (int kc = 0; kc < 2; ++kc) {
    us8 bz[4];
    #pragma unroll
    for (int nb = 0; nb < 4; ++nb)
      bz[nb] = *(const us8*)&Vl[(16 * nb + l15) * 72 + kc * 32 + g * 8];
    #pragma unroll
    for (int mm = 0; mm < 2; ++mm)
      #pragma unroll
      for (int nb = 0; nb < 4; ++nb)
        c1[mm][nb] = mfma16(a1[mm][kc], bz[nb], c1[mm][nb]);
  }

  // add bias + gathered PA/PB, relu, pack to H LDS
  #pragma unroll
  for (int mm = 0; mm < 2; ++mm) {
    float4 bb = *(const float4*)(B1 + 32 * w + 16 * mm + 4 * g);
    #pragma unroll
    for (int nb = 0; nb < 4; ++nb) {
      f4 v = c1[mm][nb];
      uint2 u0 = ga[0][mm][nb], u1 = ga[1][mm][nb];
      float h0 = v[0] + bb.x + bf2f((unsigned short)(u0.x & 0xffff))
                             + bf2f((unsigned short)(u1.x & 0xffff));
      float h1 = v[1] + bb.y + bf2f((unsigned short)(u0.x >> 16))
                             + bf2f((unsigned short)(u1.x >> 16));
      float h2 = v[2] + bb.z + bf2f((unsigned short)(u0.y & 0xffff))
                             + bf2f((unsigned short)(u1.y & 0xffff));
      float h3 = v[3] + bb.w + bf2f((unsigned short)(u0.y >> 16))
                             + bf2f((unsigned short)(u1.y >> 16));
      int er = 16 * nb + l15;
      *(uint2*)&Hl[er * 136 + 32 * w + 16 * mm + 4 * g] =
          pack4(fmaxf(h0, 0.f), fmaxf(h1, 0.f), fmaxf(h2, 0.f), fmaxf(h3, 0.f));
    }
  }
  __syncthreads();

  // layer 2: D2^T[f][e] = W2^T * H^T ; wave w owns e-block w
  f4 c2[4];
  #pragma unroll
  for (int mb = 0; mb < 4; ++mb) {
    float4 bb = *(const float4*)(B2 + 16 * mb + 4 * g);
    c2[mb] = (f4){bb.x, bb.y, bb.z, bb.w};
  }
  #pragma unroll
  for (int kc = 0; kc < 4; ++kc) {
    us8 bh = *(const us8*)&Hl[(l15 + 16 * w) * 136 + kc * 32 + g * 8];
    #pragma unroll
    for (int mb = 0; mb < 4; ++mb) {
      us8 a2 = *(const us8*)(W2T + (size_t)(16 * mb + l15) * 128 + kc * 32 + g * 8);
      c2[mb] = mfma16(a2, bh, c2[mb]);
    }
  }

  size_t e = e0 + l15 + 16 * w;
  if (PERM_OUT) {
    size_t row = (size_t)perm[e];
    #pragma unroll
    for (int mb = 0; mb < 4; ++mb) {
      int f0 = 16 * mb + 4 * g;
      *(uint2*)((unsigned short*)outv + row * 64 + f0) =
          pack4(c2[mb][0], c2[mb][1], c2[mb][2], c2[mb][3]);
    }
  } else {
    #pragma unroll
    for (int mb = 0; mb < 4; ++mb) {
      int f0 = 16 * mb + 4 * g;
      *(float4*)((float*)outv + e * 64 + f0) =
          (float4){c2[mb][0], c2[mb][1], c2[mb][2], c2[mb][3]};
    }
  }
}

// ---------------------------------------------------------------------------
// Node GEMM on MFMA, K=128. MODE 0: U = [in0(f32,64) | in1(f32,64)].
// MODE 1: U = relu(in0*sc+bi), in0 is bf16[128] if INBF else f32[128].
template<int MODE, int OUTW, bool INBF, bool OUTBF>
__global__ __launch_bounds__(256) void node_mfma(
    const void* __restrict__ in0v, const float* __restrict__ in1,
    const float* __restrict__ sc, const float* __restrict__ bi,
    const unsigned short* __restrict__ WT, const float* __restrict__ B,
    void* __restrict__ yv) {
  __shared__ __align__(16) unsigned short Ul[64 * 136];
  const int t = threadIdx.x;
  const int w = t >> 6, l = t & 63, g = l >> 4, l15 = l & 15;
  const int r0 = blockIdx.x * 64;
  constexpr int NMB = OUTW / 64;

  {
    int r = t >> 2, q = t & 3;
    int row = r0 + r;
    int rr = row < NN ? row : NN - 1;
    unsigned short tmp[32];
    if (MODE == 0) {
      const float* base = (q < 2) ? (const float*)in0v : in1;
      const float4* p = (const float4*)(base + (size_t)rr * 64 + (q & 1) * 32);
      #pragma unroll
      for (int i = 0; i < 8; ++i) {
        float4 v = p[i];
        tmp[4*i+0] = f2bf(v.x); tmp[4*i+1] = f2bf(v.y);
        tmp[4*i+2] = f2bf(v.z); tmp[4*i+3] = f2bf(v.w);
      }
    } else if (INBF) {
      const unsigned short* src = (const unsigned short*)in0v + (size_t)rr * 128 + q * 32;
      #pragma unroll
      for (int i = 0; i < 4; ++i) {
        uint4 u = *(const uint4*)(src + i * 8);
        const unsigned short* us = (const unsigned short*)&u;
        #pragma unroll
        for (int j2 = 0; j2 < 2; ++j2) {
          int cb = q * 32 + i * 8 + j2 * 4;
          float4 s = *(const float4*)(sc + cb);
          float4 b = *(const float4*)(bi + cb);
          tmp[i*8+j2*4+0] = f2bf(fmaxf(bf2f(us[j2*4+0]) * s.x + b.x, 0.f));
          tmp[i*8+j2*4+1] = f2bf(fmaxf(bf2f(us[j2*4+1]) * s.y + b.y, 0.f));
          tmp[i*8+j2*4+2] = f2bf(fmaxf(bf2f(us[j2*4+2]) * s.z + b.z, 0.f));
          tmp[i*8+j2*4+3] = f2bf(fmaxf(bf2f(us[j2*4+3]) * s.w + b.w, 0.f));
        }
      }
    } else {
      const float4* p = (const float4*)((const float*)in0v + (size_t)rr * 128 + q * 32);
      #pragma unroll
      for (int i = 0; i < 8; ++i) {
        float4 v = p[i];
        int cb = q * 32 + 4 * i;
        float4 s = *(const float4*)(sc + cb);
        float4 b = *(const float4*)(bi + cb);
        tmp[4*i+0] = f2bf(fmaxf(v.x * s.x + b.x, 0.f));
        tmp[4*i+1] = f2bf(fmaxf(v.y * s.y + b.y, 0.f));
        tmp[4*i+2] = f2bf(fmaxf(v.z * s.z + b.z, 0.f));
        tmp[4*i+3] = f2bf(fmaxf(v.w * s.w + b.w, 0.f));
      }
    }
    unsigned short* ur = &Ul[r * 136 + q * 32];
    #pragma unroll
    for (int i = 0; i < 4; ++i)
      *(uint4*)&ur[i * 8] = *(uint4*)(tmp + i * 8);
  }

  __syncthreads();

  f4 c[NMB][4];
  #pragma unroll
  for (int mm = 0; mm < NMB; ++mm) {
    float4 bb = *(const float4*)(B + 16 * (NMB * w + mm) + 4 * g);
    #pragma unroll
    for (int nb = 0; nb < 4; ++nb)
      c[mm][nb] = (f4){bb.x, bb.y, bb.z, bb.w};
  }

  #pragma unroll
  for (int kc = 0; kc < 4; ++kc) {
    us8 bu[4];
    #pragma unroll
    for (int nb = 0; nb < 4; ++nb)
      bu[nb] = *(const us8*)&Ul[(16 * nb + l15) * 136 + kc * 32 + g * 8];
    #pragma unroll
    for (int mm = 0; mm < NMB; ++mm) {
      us8 a = *(const us8*)(WT + (size_t)(16 * (NMB * w + mm) + l15) * 128
                            + kc * 32 + g * 8);
      #pragma unroll
      for (int nb = 0; nb < 4; ++nb)
        c[mm][nb] = mfma16(a, bu[nb], c[mm][nb]);
    }
  }

  #pragma unroll
  for (int mm = 0; mm < NMB; ++mm)
    #pragma unroll
    for (int nb = 0; nb < 4; ++nb) {
      int row = r0 + l15 + 16 * nb;
      if (row < NN) {
        int f0 = 16 * (NMB * w + mm) + 4 * g;
        if (OUTBF) {
          *(uint2*)((unsigned short*)yv + (size_t)row * OUTW + f0) =
              pack4(c[mm][nb][0], c[mm][nb][1], c[mm][nb][2], c[mm][nb][3]);
        } else {
          *(float4*)((float*)yv + (size_t)row * OUTW + f0) =
              (float4){c[mm][nb][0], c[mm][nb][1], c[mm][nb][2], c[mm][nb][3]};
        }
      }
    }
}

// ---------------------------------------------------------------------------
// Per-node online scatter-softmax over CSR-contiguous m rows (bf16).
__global__ void node_softmax(const unsigned short* __restrict__ m,
                             const int* __restrict__ off,
                             const float* __restrict__ tptr,
                             float* __restrict__ msg) {
  int gw = (blockIdx.x * 256 + threadIdx.x) >> 6;
  int lane = threadIdx.x & 63;
  if (gw >= NN) return;
  float t = tptr[0];
  int beg = off[gw], end = off[gw + 1];
  float M = -3e38f, S = 0.f, Wn = 0.f;
  int i = beg;
  for (; i + 1 < end; i += 2) {
    float m0 = bf2f(m[(size_t)i * 64 + lane]);
    float m1 = bf2f(m[(size_t)(i + 1) * 64 + lane]);
    float s0 = m0 * t, s1 = m1 * t;
    float Mn = fmaxf(M, fmaxf(s0, s1));
    float c = __expf(M - Mn);
    float p0 = __expf(s0 - Mn), p1 = __expf(s1 - Mn);
    S = S * c + p0 + p1;
    Wn = Wn * c + m0 * p0 + m1 * p1;
    M = Mn;
  }
  if (i < end) {
    float m0 = bf2f(m[(size_t)i * 64 + lane]);
    float s0 = m0 * t;
    float Mn = fmaxf(M, s0);
    float c = __expf(M - Mn);
    float p0 = __expf(s0 - Mn);
    S = S * c + p0;
    Wn = Wn * c + m0 * p0;
    M = Mn;
  }
  msg[(size_t)gw * 64 + lane] = (end > beg) ? (Wn / S) : 0.f;
}

// ---------------------------------------------------------------------------
extern "C" void kernel_launch(void* const* d_in, const int* in_sizes, int n_in,
                              void* d_out, int out_size, void* d_ws, size_t ws_size,
                              hipStream_t stream) {
  const float* x     = (const float*)d_in[0];
  const int*   ei    = (const int*)d_in[1];
  const float* ea    = (const float*)d_in[2];
  const float* gh_w  = (const float*)d_in[3];
  const float* gh_b  = (const float*)d_in[4];
  const float* gv_w  = (const float*)d_in[5];
  const float* gv_b  = (const float*)d_in[6];
  const float* tpar  = (const float*)d_in[7];
  const float* p_w1  = (const float*)d_in[8];
  const float* p_b1  = (const float*)d_in[9];
  const float* p_w2  = (const float*)d_in[10];
  const float* p_b2  = (const float*)d_in[11];
  const float* h_w1  = (const float*)d_in[12];
  const float* h_b1  = (const float*)d_in[13];
  const float* h_g1  = (const float*)d_in[14];
  const float* h_bb1 = (const float*)d_in[15];
  const float* h_w2  = (const float*)d_in[16];
  const float* h_b2  = (const float*)d_in[17];
  const float* h_g2  = (const float*)d_in[18];
  const float* h_bb2 = (const float*)d_in[19];
  const float* h_w3  = (const float*)d_in[20];
  const float* h_b3  = (const float*)d_in[21];
  const float* h_g3  = (const float*)d_in[22];
  const float* h_bb3 = (const float*)d_in[23];
  const float* h_w4  = (const float*)d_in[24];
  const float* h_b4  = (const float*)d_in[25];
  const float* e_w1  = (const float*)d_in[26];
  const float* e_b1  = (const float*)d_in[27];
  const float* e_w2  = (const float*)d_in[28];
  const float* e_b2  = (const float*)d_in[29];

  float* h_out = (float*)d_out;
  float* v_out = (float*)d_out + (size_t)NN * 64;

  const int* src = ei;
  const int* dst = ei + NE;

  char* w = (char*)d_ws;
  // zeroed region: stats (4KB) + cnt + cursor
  float* stats = (float*)w;
  float* xsum = stats + 0,   *xsq = stats + 64;
  float* vsum = stats + 128, *vsq = stats + 192;
  float* ys1  = stats + 256, *yq1 = stats + 384;
  float* ys2  = stats + 512, *yq2 = stats + 640;
  float* ys3  = stats + 768, *yq3 = stats + 896;
  int* cnt    = (int*)(w + 4096);
  int* cursor = (int*)(w + 4096 + 200704);
  size_t zero_bytes = 4096 + 2 * 200704;

  char* p = w + zero_bytes;
  float* sb = (float*)p; p += 4096;
  float* sbx_s = sb,       *sbx_b = sb + 64;
  float* sbv_s = sb + 128, *sbv_b = sb + 192;
  float* sb1_s = sb + 256, *sb1_b = sb + 384;
  float* sb2_s = sb + 512, *sb2_b = sb + 640;
  float* sb3_s = sb + 768, *sb3_b = sb + 896;
  int* off    = (int*)p; p += 200704;
  int* perm   = (int*)p; p += (size_t)NE * 4;
  float* h    = (float*)p; p += (size_t)NN * 64 * 4;
  float* msg  = (float*)p; p += (size_t)NN * 64 * 4;
  unsigned short* vbf  = (unsigned short*)p; p += (size_t)NE * 64 * 2;
  unsigned short* m_bf = (unsigned short*)p; p += (size_t)NE * 64 * 2;
  unsigned short* PAB  = (unsigned short*)p; p += (size_t)NN * 256 * 2;
  unsigned short* QAB  = (unsigned short*)p; p += (size_t)NN * 256 * 2;
  unsigned short* y1   = (unsigned short*)p; p += (size_t)NN * 128 * 2;
  unsigned short* y2   = (unsigned short*)p; p += (size_t)NN * 128 * 2;
  unsigned short* wpab  = (unsigned short*)p; p += 256 * 64 * 2;
  unsigned short* wqab  = (unsigned short*)p; p += 256 * 64 * 2;
  unsigned short* w1c_p = (unsigned short*)p; p += 128 * 64 * 2;
  unsigned short* w1c_e = (unsigned short*)p; p += 128 * 64 * 2;
  unsigned short* w2t_p = (unsigned short*)p; p += 64 * 128 * 2;
  unsigned short* w2t_e = (unsigned short*)p; p += 64 * 128 * 2;
  unsigned short* h_w1t = (unsigned short*)p; p += 128 * 128 * 2;
  unsigned short* h_w2t = (unsigned short*)p; p += 128 * 128 * 2;
  unsigned short* h_w3t = (unsigned short*)p; p += 128 * 128 * 2;
  unsigned short* h_w4t = (unsigned short*)p; p += 64 * 128 * 2;

  hipMemsetAsync(d_ws, 0, zero_bytes, stream);

  // weight prep
  wtrans_pair<<<64, 256, 0, stream>>>(p_w1, wpab);
  wtrans_pair<<<64, 256, 0, stream>>>(e_w1, wqab);
  wtrans<<<32, 256, 0, stream>>>(p_w1 + 128 * 128, w1c_p, 64, 128);
  wtrans<<<32, 256, 0, stream>>>(e_w1 + 128 * 128, w1c_e, 64, 128);
  wtrans<<<32, 256, 0, stream>>>(p_w2, w2t_p, 128, 64);
  wtrans<<<32, 256, 0, stream>>>(e_w2, w2t_e, 128, 64);
  wtrans<<<64, 256, 0, stream>>>(h_w1, h_w1t, 128, 128);
  wtrans<<<64, 256, 0, stream>>>(h_w2, h_w2t, 128, 128);
  wtrans<<<64, 256, 0, stream>>>(h_w3, h_w3t, 128, 128);
  wtrans<<<32, 256, 0, stream>>>(h_w4, h_w4t, 128, 64);

  // BN stats + normalize
  colstats<64><<<256, 256, 0, stream>>>(x, NN, xsum, xsq);
  colstats<64><<<1024, 256, 0, stream>>>(ea, NE, vsum, vsq);
  finalize_sb<<<1, 64, 0, stream>>>(xsum, xsq, 1.0f / NN, gh_w, gh_b, sbx_s, sbx_b, 64);
  finalize_sb<<<1, 64, 0, stream>>>(vsum, vsq, 1.0f / NE, gv_w, gv_b, sbv_s, sbv_b, 64);
  bn_relu64<<<3125, 256, 0, stream>>>(x, sbx_s, sbx_b, h);
  bn_relu_bf<<<25000, 256, 0, stream>>>(ea, sbv_s, sbv_b, vbf);

  // CSR (dst) for softmax segments
  count_edges<<<3125, 256, 0, stream>>>(dst, cnt);
  scan_offsets<<<1, 1024, 0, stream>>>(cnt, off);
  fill_perm<<<3125, 256, 0, stream>>>(dst, off, cursor, perm);

  // node-side factor of message MLP layer 1: PAB = h @ [pW1a | pW1b]
  pab_gemm<<<782, 256, 0, stream>>>(h, wpab, PAB);

  // message MLP: tbl0 = dst (pW1a), tbl1 = src (pW1b); out -> m_bf at perm
  edge_mlp2<true><<<12500, 256, 0, stream>>>(vbf, PAB, dst, src,
                                             w1c_p, p_b1, w2t_p, p_b2, perm, (void*)m_bf);

  // scatter-softmax aggregation (contiguous rows)
  node_softmax<<<12500, 256, 0, stream>>>(m_bf, off, tpar, msg);

  // node MLP chain with BN between layers (bf16 intermediates)
  node_mfma<0, 128, false, true><<<782, 256, 0, stream>>>(
      h, msg, nullptr, nullptr, h_w1t, h_b1, (void*)y1);
  colstats_bf<128><<<512, 256, 0, stream>>>(y1, NN, ys1, yq1);
  finalize_sb<<<1, 128, 0, stream>>>(ys1, yq1, 1.0f / NN, h_g1, h_bb1, sb1_s, sb1_b, 128);

  node_mfma<1, 128, true, true><<<782, 256, 0, stream>>>(
      y1, nullptr, sb1_s, sb1_b, h_w2t, h_b2, (void*)y2);
  colstats_bf<128><<<512, 256, 0, stream>>>(y2, NN, ys2, yq2);
  finalize_sb<<<1, 128, 0, stream>>>(ys2, yq2, 1.0f / NN, h_g2, h_bb2, sb2_s, sb2_b, 128);

  node_mfma<1, 128, true, true><<<782, 256, 0, stream>>>(
      y2, nullptr, sb2_s, sb2_b, h_w3t, h_b3, (void*)y1);
  colstats_bf<128><<<512, 256, 0, stream>>>(y1, NN, ys3, yq3);
  finalize_sb<<<1, 128, 0, stream>>>(ys3, yq3, 1.0f / NN, h_g3, h_bb3, sb3_s, sb3_b, 128);

  node_mfma<1, 64, true, false><<<782, 256, 0, stream>>>(
      y1, nullptr, sb3_s, sb3_b, h_w4t, h_b4, (void*)h_out);

  // node-side factor of edge-output MLP: QAB = relu(h_out) @ [eW1a | eW1b]
  pab_gemm<<<782, 256, 0, stream>>>(h_out, wqab, QAB);

  // edge output MLP: tbl0 = src (eW1a), tbl1 = dst (eW1b); out -> v_out f32
  edge_mlp2<false><<<12500, 256, 0, stream>>>(vbf, QAB, src, dst,
                                              w1c_e, e_b1, w2t_e, e_b2, nullptr, (void*)v_out);
}

// Round 4
// 900.209 us; speedup vs baseline: 3.5373x; 1.1602x over previous
//
#include <hip/hip_runtime.h>
#include <math.h>

#define NN 50000
#define NE 800000

typedef __attribute__((ext_vector_type(8))) unsigned short us8;
typedef __attribute__((ext_vector_type(8))) __bf16 bf8;
typedef __attribute__((ext_vector_type(4))) float f4;

__device__ __forceinline__ unsigned short f2bf(float f) {
  unsigned int u = __float_as_uint(f);
  unsigned int r = u + 0x7FFFu + ((u >> 16) & 1u);
  return (unsigned short)(r >> 16);
}
__device__ __forceinline__ float bf2f(unsigned short h) {
  return __uint_as_float(((unsigned int)h) << 16);
}
__device__ __forceinline__ f4 mfma16(us8 a, us8 b, f4 c) {
  return __builtin_amdgcn_mfma_f32_16x16x32_bf16(
      __builtin_bit_cast(bf8, a), __builtin_bit_cast(bf8, b), c, 0, 0, 0);
}
__device__ __forceinline__ uint2 pack4(float a, float b, float c, float d) {
  uint2 r;
  r.x = (unsigned)f2bf(a) | ((unsigned)f2bf(b) << 16);
  r.y = (unsigned)f2bf(c) | ((unsigned)f2bf(d) << 16);
  return r;
}

// ---------------------------------------------------------------------------
// Column stats (sum, sumsq) for BN over f32 input.
template<int C>
__global__ void colstats(const float* __restrict__ x, int rows,
                         float* __restrict__ sum, float* __restrict__ sq) {
  constexpr int RL = 256 / C;
  int c = threadIdx.x % C;
  int r0 = threadIdx.x / C;
  float s = 0.f, q = 0.f;
  for (int r = blockIdx.x * RL + r0; r < rows; r += gridDim.x * RL) {
    float v = x[(size_t)r * C + c];
    s += v; q += v * v;
  }
  __shared__ float ls[256], lq[256];
  ls[threadIdx.x] = s; lq[threadIdx.x] = q;
  __syncthreads();
  if (r0 == 0) {
    #pragma unroll
    for (int i = 1; i < RL; ++i) { s += ls[i * C + c]; q += lq[i * C + c]; }
    atomicAdd(&sum[c], s);
    atomicAdd(&sq[c], q);
  }
}

// finalize scale/bias for x (block 0) and edge_attr (block 1)
__global__ void finalize2(const float* __restrict__ stats,
                          const float* __restrict__ gh_w, const float* __restrict__ gh_b,
                          const float* __restrict__ gv_w, const float* __restrict__ gv_b,
                          float* __restrict__ sb) {
  int c = threadIdx.x;
  if (c >= 64) return;
  if (blockIdx.x == 0) {
    float mu = stats[c] * (1.0f / NN);
    float var = stats[64 + c] * (1.0f / NN) - mu * mu;
    float sc = gh_w[c] * rsqrtf(var + 1e-5f);
    sb[c] = sc; sb[64 + c] = gh_b[c] - mu * sc;
  } else {
    float mu = stats[128 + c] * (1.0f / NE);
    float var = stats[192 + c] * (1.0f / NE) - mu * mu;
    float sc = gv_w[c] * rsqrtf(var + 1e-5f);
    sb[128 + c] = sc; sb[192 + c] = gv_b[c] - mu * sc;
  }
}

__global__ void finalize_sb(const float* __restrict__ sum, const float* __restrict__ sq,
                            float inv_rows,
                            const float* __restrict__ g, const float* __restrict__ b,
                            float* __restrict__ scale, float* __restrict__ bias, int C) {
  int c = threadIdx.x;
  if (c < C) {
    float mu = sum[c] * inv_rows;
    float var = sq[c] * inv_rows - mu * mu;
    float sc = g[c] * rsqrtf(var + 1e-5f);
    scale[c] = sc;
    bias[c] = b[c] - mu * sc;
  }
}

// vbf_perm[perm[e]] = bf16(relu(ea[e]*scale+bias)); 8 elems/thread
__global__ void bn_scatter(const float* __restrict__ ea, const float* __restrict__ sc,
                           const float* __restrict__ bi, const int* __restrict__ perm,
                           unsigned short* __restrict__ vbf) {
  size_t i = (size_t)blockIdx.x * 256 + threadIdx.x;   // 8-elem chunk
  int e = (int)(i >> 3), q = (int)(i & 7);
  int c8 = q * 8;
  const float4* px = (const float4*)(ea + (size_t)e * 64 + c8);
  float4 a = px[0], b = px[1];
  float4 s0 = *(const float4*)(sc + c8), s1 = *(const float4*)(sc + c8 + 4);
  float4 b0 = *(const float4*)(bi + c8),  b1 = *(const float4*)(bi + c8 + 4);
  unsigned short tmp[8];
  tmp[0] = f2bf(fmaxf(a.x * s0.x + b0.x, 0.f));
  tmp[1] = f2bf(fmaxf(a.y * s0.y + b0.y, 0.f));
  tmp[2] = f2bf(fmaxf(a.z * s0.z + b0.z, 0.f));
  tmp[3] = f2bf(fmaxf(a.w * s0.w + b0.w, 0.f));
  tmp[4] = f2bf(fmaxf(b.x * s1.x + b1.x, 0.f));
  tmp[5] = f2bf(fmaxf(b.y * s1.y + b1.y, 0.f));
  tmp[6] = f2bf(fmaxf(b.z * s1.z + b1.z, 0.f));
  tmp[7] = f2bf(fmaxf(b.w * s1.w + b1.w, 0.f));
  *(uint4*)(vbf + (size_t)perm[e] * 64 + c8) = *(uint4*)tmp;
}

// ---------------------------------------------------------------------------
// Fused weight prep: all transposes/converts in one launch. 480 blocks.
__global__ void wprep(const float* __restrict__ p_w1, const float* __restrict__ e_w1,
                      const float* __restrict__ p_w2, const float* __restrict__ e_w2,
                      const float* __restrict__ h_w1, const float* __restrict__ h_w2,
                      const float* __restrict__ h_w3, const float* __restrict__ h_w4,
                      unsigned short* __restrict__ wpab, unsigned short* __restrict__ wqab,
                      unsigned short* __restrict__ w1c_p, unsigned short* __restrict__ w1c_e,
                      unsigned short* __restrict__ w2f_p, unsigned short* __restrict__ w2f_e,
                      unsigned short* __restrict__ hw1t, unsigned short* __restrict__ hw2t,
                      unsigned short* __restrict__ hw3t, unsigned short* __restrict__ hw4t) {
  int gi = blockIdx.x * 256 + threadIdx.x;
  if (gi < 32768) {                        // wpab / wqab
    const float* w = (gi < 16384) ? p_w1 : e_w1;
    unsigned short* o = (gi < 16384) ? wpab : wqab;
    int i = gi & 16383;
    int f = i >> 6, k = i & 63;
    int srcrow = k + ((f >> 7) << 6);
    o[i] = f2bf(w[(size_t)srcrow * 128 + (f & 127)]);
  } else if (gi < 49152) {                 // w1c_p / w1c_e
    int i = (gi - 32768) & 8191;
    const float* w = (gi < 40960) ? (p_w1 + 128 * 128) : (e_w1 + 128 * 128);
    unsigned short* o = (gi < 40960) ? w1c_p : w1c_e;
    int f = i >> 6, k = i & 63;
    o[i] = f2bf(w[(size_t)k * 128 + f]);
  } else if (gi < 65536) {                 // w2f_p / w2f_e (fragment-linear)
    int i = (gi - 49152) & 8191;
    const float* w = (gi < 57344) ? p_w2 : e_w2;
    unsigned short* o = (gi < 57344) ? w2f_p : w2f_e;
    int j = i & 7, lane = (i >> 3) & 63, frag = i >> 9;
    int kc = frag & 3, mb = frag >> 2;
    int l15 = lane & 15, g = lane >> 4;
    o[i] = f2bf(w[(size_t)(kc * 32 + g * 8 + j) * 64 + 16 * mb + l15]);
  } else if (gi < 114688) {                // hw1t/hw2t/hw3t [128][128]
    int seg = (gi - 65536) >> 14;
    int i = (gi - 65536) & 16383;
    const float* w = (seg == 0) ? h_w1 : (seg == 1) ? h_w2 : h_w3;
    unsigned short* o = (seg == 0) ? hw1t : (seg == 1) ? hw2t : hw3t;
    int n = i >> 7, k = i & 127;
    o[i] = f2bf(w[(size_t)k * 128 + n]);
  } else if (gi < 122880) {                // hw4t [64][128]
    int i = gi - 114688;
    int n = i >> 7, k = i & 127;
    hw4t[i] = f2bf(h_w4[(size_t)k * 64 + n]);
  }
}

// ---------------------------------------------------------------------------
// CSR build: count -> hierarchical scan -> fill (perm + sorted idx arrays)
__global__ void count_edges(const int* __restrict__ dst, int* __restrict__ cnt) {
  int e = blockIdx.x * 256 + threadIdx.x;
  atomicAdd(&cnt[dst[e]], 1);
}

__global__ void scan_part(const int* __restrict__ cnt, int* __restrict__ bsum) {
  __shared__ int ls[256];
  int i = blockIdx.x * 256 + threadIdx.x;
  ls[threadIdx.x] = (i < NN) ? cnt[i] : 0;
  __syncthreads();
  for (int d = 128; d > 0; d >>= 1) {
    if (threadIdx.x < d) ls[threadIdx.x] += ls[threadIdx.x + d];
    __syncthreads();
  }
  if (threadIdx.x == 0) bsum[blockIdx.x] = ls[0];
}

__global__ void scan_top(int* __restrict__ bsum) {
  __shared__ int ps[256];
  int t = threadIdx.x;
  int v = (t < 196) ? bsum[t] : 0;
  ps[t] = v;
  __syncthreads();
  for (int d = 1; d < 256; d <<= 1) {
    int tv = (t >= d) ? ps[t - d] : 0;
    __syncthreads();
    ps[t] += tv;
    __syncthreads();
  }
  if (t < 196) bsum[t] = ps[t] - v;   // exclusive
}

__global__ void scan_add(const int* __restrict__ cnt, const int* __restrict__ bsum,
                         int* __restrict__ off) {
  __shared__ int ps[256];
  int t = threadIdx.x;
  int i = blockIdx.x * 256 + t;
  int v = (i < NN) ? cnt[i] : 0;
  ps[t] = v;
  __syncthreads();
  for (int d = 1; d < 256; d <<= 1) {
    int tv = (t >= d) ? ps[t - d] : 0;
    __syncthreads();
    ps[t] += tv;
    __syncthreads();
  }
  if (i < NN) off[i] = bsum[blockIdx.x] + ps[t] - v;
  if (blockIdx.x == 0 && t == 0) off[NN] = NE;
}

__global__ void fill_perm(const int* __restrict__ srca, const int* __restrict__ dsta,
                          const int* __restrict__ off, int* __restrict__ cursor,
                          int* __restrict__ perm, int* __restrict__ src_s,
                          int* __restrict__ dst_s) {
  int e = blockIdx.x * 256 + threadIdx.x;
  int n = dsta[e];
  int p = atomicAdd(&cursor[n], 1);
  int pos = off[n] + p;
  perm[e] = pos;
  dst_s[pos] = n;
  src_s[pos] = srca[e];
}

// ---------------------------------------------------------------------------
// PAB = bf16( relu([bn](in)) @ WT^T ), written in gather-swizzled order.
// BN: apply per-col scale/bias first. WRITEH: also write staged rows as f32.
template<bool BN, bool WRITEH>
__global__ __launch_bounds__(256) void pab_gemm(
    const float* __restrict__ in, const float* __restrict__ sc,
    const float* __restrict__ bi, const unsigned short* __restrict__ WT,
    unsigned short* __restrict__ out, float* __restrict__ hout) {
  __shared__ __align__(16) unsigned short Ul[64 * 72];
  const int t = threadIdx.x;
  const int w = t >> 6, l = t & 63, g = l >> 4, l15 = l & 15;
  const int r0 = blockIdx.x * 64;

  #pragma unroll
  for (int it = 0; it < 2; ++it) {
    int idx = it * 256 + t;
    int r = idx >> 3, q = idx & 7;
    int row = r0 + r; int rr = row < NN ? row : NN - 1;
    float4 v = *(const float4*)(in + (size_t)rr * 64 + q * 8);
    float4 v2 = *(const float4*)(in + (size_t)rr * 64 + q * 8 + 4);
    if (BN) {
      float4 s0 = *(const float4*)(sc + q * 8), s1 = *(const float4*)(sc + q * 8 + 4);
      float4 c0 = *(const float4*)(bi + q * 8), c1 = *(const float4*)(bi + q * 8 + 4);
      v.x = v.x * s0.x + c0.x;   v.y = v.y * s0.y + c0.y;
      v.z = v.z * s0.z + c0.z;   v.w = v.w * s0.w + c0.w;
      v2.x = v2.x * s1.x + c1.x; v2.y = v2.y * s1.y + c1.y;
      v2.z = v2.z * s1.z + c1.z; v2.w = v2.w * s1.w + c1.w;
    }
    v.x = fmaxf(v.x, 0.f);  v.y = fmaxf(v.y, 0.f);
    v.z = fmaxf(v.z, 0.f);  v.w = fmaxf(v.w, 0.f);
    v2.x = fmaxf(v2.x, 0.f); v2.y = fmaxf(v2.y, 0.f);
    v2.z = fmaxf(v2.z, 0.f); v2.w = fmaxf(v2.w, 0.f);
    unsigned short tmp[8];
    tmp[0] = f2bf(v.x);  tmp[1] = f2bf(v.y);  tmp[2] = f2bf(v.z);  tmp[3] = f2bf(v.w);
    tmp[4] = f2bf(v2.x); tmp[5] = f2bf(v2.y); tmp[6] = f2bf(v2.z); tmp[7] = f2bf(v2.w);
    *(uint4*)&Ul[r * 72 + q * 8] = *(uint4*)tmp;
    if (WRITEH && row < NN) {
      *(float4*)(hout + (size_t)row * 64 + q * 8) = v;
      *(float4*)(hout + (size_t)row * 64 + q * 8 + 4) = v2;
    }
  }
  us8 a[4][2];
  #pragma unroll
  for (int mm = 0; mm < 4; ++mm)
    #pragma unroll
    for (int kc = 0; kc < 2; ++kc)
      a[mm][kc] = *(const us8*)(WT + (size_t)(64 * w + 16 * mm + l15) * 64 + kc * 32 + g * 8);
  __syncthreads();

  f4 c[4][4];
  #pragma unroll
  for (int mm = 0; mm < 4; ++mm)
    #pragma unroll
    for (int nb = 0; nb < 4; ++nb)
      c[mm][nb] = (f4){0.f, 0.f, 0.f, 0.f};
  #pragma unroll
  for (int kc = 0; kc < 2; ++kc) {
    us8 bz[4];
    #pragma unroll
    for (int nb = 0; nb < 4; ++nb)
      bz[nb] = *(const us8*)&Ul[(16 * nb + l15) * 72 + kc * 32 + g * 8];
    #pragma unroll
    for (int mm = 0; mm < 4; ++mm)
      #pragma unroll
      for (int nb = 0; nb < 4; ++nb)
        c[mm][nb] = mfma16(a[mm][kc], bz[nb], c[mm][nb]);
  }
  #pragma unroll
  for (int mm = 0; mm < 4; ++mm)
    #pragma unroll
    for (int nb = 0; nb < 4; ++nb) {
      int row = r0 + 16 * nb + l15;
      if (row < NN) {
        int f0 = 64 * w + 16 * mm + 4 * g;   // logical f
        // swizzle: f = half*128 + f1; pos = half*128 + 32*(f1>>5) + 8*((f1&15)>>2) + 4*((f1>>4)&1)
        int half = f0 >> 7;
        int f1 = f0 & 127;
        int pos = half * 128 + ((f1 >> 5) << 5) + (((f1 & 15) >> 2) << 3) + (((f1 >> 4) & 1) << 2);
        *(uint2*)(out + (size_t)row * 256 + pos) =
            pack4(c[mm][nb][0], c[mm][nb][1], c[mm][nb][2], c[mm][nb][3]);
      }
    }
}

// ---------------------------------------------------------------------------
// Edge MLP. MODE 1: CSR-sorted order, m (bf16) contiguous out, XCD swizzle.
// MODE 2: original order, v_out (f32), vbf gathered via perm.
// hidden = relu(PAB[n0][f] + PAB[n1][128+f] + (v@W1c)[f] + B1[f]); out = hidden@W2+B2
template<int MODE>
__global__ __launch_bounds__(256, 4) void edge_mlp3(
    const unsigned short* __restrict__ vbf,     // perm-order rows
    const unsigned short* __restrict__ PAB,     // swizzled
    const int* __restrict__ idx0, const int* __restrict__ idx1,
    const int* __restrict__ perm,
    const unsigned short* __restrict__ W1cT, const float* __restrict__ B1,
    const unsigned short* __restrict__ W2F, const float* __restrict__ B2,
    void* __restrict__ outv) {
  __shared__ __align__(16) unsigned short W2l[8192];
  __shared__ __align__(16) unsigned short UN[64 * 136];   // Vl[64][72] then Hl[64][136]
  const int t = threadIdx.x;
  const int w = t >> 6, l = t & 63, g = l >> 4, l15 = l & 15;
  int bid = blockIdx.x;
  if (MODE == 1) {   // bijective XCD-chunked swizzle (nwg=12500, 8 XCDs)
    const int q = 12500 / 8, r = 12500 % 8;
    int x = bid % 8, j = bid / 8;
    bid = (x < r ? x * (q + 1) : r * (q + 1) + (x - r) * q) + j;
  }
  const size_t e0 = (size_t)bid * 64;

  // ---- phase 0: stage V, issue gathers, stage W2 to LDS, load W1c frags
  {
    int r_ = t >> 2, q_ = t & 3;
    size_t row = (MODE == 1) ? (e0 + r_) : (size_t)perm[e0 + r_];
    const uint4* pv = (const uint4*)(vbf + row * 64 + q_ * 16);
    uint4 v0 = pv[0], v1 = pv[1];
    *(uint4*)&UN[r_ * 72 + q_ * 16] = v0;
    *(uint4*)&UN[r_ * 72 + q_ * 16 + 8] = v1;
  }
  uint4 ga0[4], ga1[4];
  #pragma unroll
  for (int nb = 0; nb < 4; ++nb) {
    size_t e = e0 + 16 * nb + l15;
    int n0 = idx0[e], n1 = idx1[e];
    ga0[nb] = *(const uint4*)(PAB + (size_t)n0 * 256 + w * 32 + g * 8);
    ga1[nb] = *(const uint4*)(PAB + (size_t)n1 * 256 + 128 + w * 32 + g * 8);
  }
  #pragma unroll
  for (int i = 0; i < 4; ++i) {
    uint4 v = *(const uint4*)(W2F + (size_t)(t + 256 * i) * 8);
    *(uint4*)&W2l[(t + 256 * i) * 8] = v;
  }
  us8 a1[2][2];
  #pragma unroll
  for (int mm = 0; mm < 2; ++mm)
    #pragma unroll
    for (int kc = 0; kc < 2; ++kc)
      a1[mm][kc] = *(const us8*)(W1cT + (size_t)(32 * w + 16 * mm + l15) * 64
                                 + kc * 32 + g * 8);
  __syncthreads();

  // ---- phase 1: layer 1 MFMA (EV^T = W1c^T * V^T)
  f4 c1[2][4];
  #pragma unroll
  for (int mm = 0; mm < 2; ++mm)
    #pragma unroll
    for (int nb = 0; nb < 4; ++nb)
      c1[mm][nb] = (f4){0.f, 0.f, 0.f, 0.f};
  #pragma unroll
  for (int kc = 0; kc < 2; ++kc) {
    us8 bz[4];
    #pragma unroll
    for (int nb = 0; nb < 4; ++nb)
      bz[nb] = *(const us8*)&UN[(16 * nb + l15) * 72 + kc * 32 + g * 8];
    #pragma unroll
    for (int mm = 0; mm < 2; ++mm)
      #pragma unroll
      for (int nb = 0; nb < 4; ++nb)
        c1[mm][nb] = mfma16(a1[mm][kc], bz[nb], c1[mm][nb]);
  }
  __syncthreads();   // all Vl reads done before Hl overwrite

  // ---- phase 2: H = relu(c1 + B1 + ga0 + ga1) -> Hl (bf16)
  #pragma unroll
  for (int mm = 0; mm < 2; ++mm) {
    float4 bb = *(const float4*)(B1 + 32 * w + 16 * mm + 4 * g);
    #pragma unroll
    for (int nb = 0; nb < 4; ++nb) {
      f4 v = c1[mm][nb];
      unsigned int ux = mm ? ga0[nb].z : ga0[nb].x;
      unsigned int uy = mm ? ga0[nb].w : ga0[nb].y;
      unsigned int vx = mm ? ga1[nb].z : ga1[nb].x;
      unsigned int vy = mm ? ga1[nb].w : ga1[nb].y;
      float h0 = v[0] + bb.x + bf2f((unsigned short)(ux & 0xffff))
                             + bf2f((unsigned short)(vx & 0xffff));
      float h1 = v[1] + bb.y + bf2f((unsigned short)(ux >> 16))
                             + bf2f((unsigned short)(vx >> 16));
      float h2 = v[2] + bb.z + bf2f((unsigned short)(uy & 0xffff))
                             + bf2f((unsigned short)(vy & 0xffff));
      float h3 = v[3] + bb.w + bf2f((unsigned short)(uy >> 16))
                             + bf2f((unsigned short)(vy >> 16));
      int er = 16 * nb + l15;
      *(uint2*)&UN[er * 136 + 32 * w + 16 * mm + 4 * g] =
          pack4(fmaxf(h0, 0.f), fmaxf(h1, 0.f), fmaxf(h2, 0.f), fmaxf(h3, 0.f));
    }
  }
  __syncthreads();

  // ---- phase 3: layer 2 (D2^T = W2^T * H^T), W2 frags from LDS (lane-linear)
  f4 c2[4];
  #pragma unroll
  for (int mb = 0; mb < 4; ++mb) {
    float4 bb = *(const float4*)(B2 + 16 * mb + 4 * g);
    c2[mb] = (f4){bb.x, bb.y, bb.z, bb.w};
  }
  #pragma unroll
  for (int kc = 0; kc < 4; ++kc) {
    us8 bh = *(const us8*)&UN[(16 * w + l15) * 136 + kc * 32 + g * 8];
    #pragma unroll
    for (int mb = 0; mb < 4; ++mb) {
      us8 a2 = *(const us8*)&W2l[((mb * 4 + kc) * 64 + l) * 8];
      c2[mb] = mfma16(a2, bh, c2[mb]);
    }
  }

  size_t e = e0 + 16 * w + l15;
  if (MODE == 1) {
    #pragma unroll
    for (int mb = 0; mb < 4; ++mb)
      *(uint2*)((unsigned short*)outv + e * 64 + 16 * mb + 4 * g) =
          pack4(c2[mb][0], c2[mb][1], c2[mb][2], c2[mb][3]);
  } else {
    #pragma unroll
    for (int mb = 0; mb < 4; ++mb)
      *(float4*)((float*)outv + e * 64 + 16 * mb + 4 * g) =
          (float4){c2[mb][0], c2[mb][1], c2[mb][2], c2[mb][3]};
  }
}

// ---------------------------------------------------------------------------
// Node GEMM on MFMA, K=128, optional fused column-stats epilogue.
// MODE 0: U = [in0(f32,64)|in1(f32,64)]. MODE 1: U = relu(in0*sc+bi), in0 bf16[128].
template<int MODE, int OUTW, bool INBF, bool OUTBF, bool STATS>
__global__ __launch_bounds__(256) void node_mfma(
    const void* __restrict__ in0v, const float* __restrict__ in1,
    const float* __restrict__ sc, const float* __restrict__ bi,
    const unsigned short* __restrict__ WT, const float* __restrict__ B,
    void* __restrict__ yv, float* __restrict__ ysum, float* __restrict__ ysq) {
  __shared__ __align__(16) unsigned short Ul[64 * 136];
  const int t = threadIdx.x;
  const int w = t >> 6, l = t & 63, g = l >> 4, l15 = l & 15;
  const int r0 = blockIdx.x * 64;
  constexpr int NMB = OUTW / 64;

  {
    int r = t >> 2, q = t & 3;
    int row = r0 + r;
    int rr = row < NN ? row : NN - 1;
    unsigned short tmp[32];
    if (MODE == 0) {
      const float* base = (q < 2) ? (const float*)in0v : in1;
      const float4* p = (const float4*)(base + (size_t)rr * 64 + (q & 1) * 32);
      #pragma unroll
      for (int i = 0; i < 8; ++i) {
        float4 v = p[i];
        tmp[4*i+0] = f2bf(v.x); tmp[4*i+1] = f2bf(v.y);
        tmp[4*i+2] = f2bf(v.z); tmp[4*i+3] = f2bf(v.w);
      }
    } else if (INBF) {
      const unsigned short* src = (const unsigned short*)in0v + (size_t)rr * 128 + q * 32;
      #pragma unroll
      for (int i = 0; i < 4; ++i) {
        uint4 u = *(const uint4*)(src + i * 8);
        const unsigned short* us = (const unsigned short*)&u;
        #pragma unroll
        for (int j2 = 0; j2 < 2; ++j2) {
          int cb = q * 32 + i * 8 + j2 * 4;
          float4 s = *(const float4*)(sc + cb);
          float4 b = *(const float4*)(bi + cb);
          tmp[i*8+j2*4+0] = f2bf(fmaxf(bf2f(us[j2*4+0]) * s.x + b.x, 0.f));
          tmp[i*8+j2*4+1] = f2bf(fmaxf(bf2f(us[j2*4+1]) * s.y + b.y, 0.f));
          tmp[i*8+j2*4+2] = f2bf(fmaxf(bf2f(us[j2*4+2]) * s.z + b.z, 0.f));
          tmp[i*8+j2*4+3] = f2bf(fmaxf(bf2f(us[j2*4+3]) * s.w + b.w, 0.f));
        }
      }
    }
    unsigned short* ur = &Ul[r * 136 + q * 32];
    #pragma unroll
    for (int i = 0; i < 4; ++i)
      *(uint4*)&ur[i * 8] = *(uint4*)(tmp + i * 8);
  }

  __syncthreads();

  f4 c[NMB][4];
  #pragma unroll
  for (int mm = 0; mm < NMB; ++mm) {
    float4 bb = *(const float4*)(B + 16 * (NMB * w + mm) + 4 * g);
    #pragma unroll
    for (int nb = 0; nb < 4; ++nb)
      c[mm][nb] = (f4){bb.x, bb.y, bb.z, bb.w};
  }

  #pragma unroll
  for (int kc = 0; kc < 4; ++kc) {
    us8 bu[4];
    #pragma unroll
    for (int nb = 0; nb < 4; ++nb)
      bu[nb] = *(const us8*)&Ul[(16 * nb + l15) * 136 + kc * 32 + g * 8];
    #pragma unroll
    for (int mm = 0; mm < NMB; ++mm) {
      us8 a = *(const us8*)(WT + (size_t)(16 * (NMB * w + mm) + l15) * 128
                            + kc * 32 + g * 8);
      #pragma unroll
      for (int nb = 0; nb < 4; ++nb)
        c[mm][nb] = mfma16(a, bu[nb], c[mm][nb]);
    }
  }

  #pragma unroll
  for (int mm = 0; mm < NMB; ++mm)
    #pragma unroll
    for (int nb = 0; nb < 4; ++nb) {
      int row = r0 + l15 + 16 * nb;
      if (row < NN) {
        int f0 = 16 * (NMB * w + mm) + 4 * g;
        if (OUTBF) {
          *(uint2*)((unsigned short*)yv + (size_t)row * OUTW + f0) =
              pack4(c[mm][nb][0], c[mm][nb][1], c[mm][nb][2], c[mm][nb][3]);
        } else {
          *(float4*)((float*)yv + (size_t)row * OUTW + f0) =
              (float4){c[mm][nb][0], c[mm][nb][1], c[mm][nb][2], c[mm][nb][3]};
        }
      }
    }

  if (STATS) {
    float msk[4];
    #pragma unroll
    for (int nb = 0; nb < 4; ++nb)
      msk[nb] = (r0 + 16 * nb + l15 < NN) ? 1.f : 0.f;
    #pragma unroll
    for (int mm = 0; mm < NMB; ++mm)
      #pragma unroll
      for (int r = 0; r < 4; ++r) {
        float s = 0.f, q = 0.f;
        #pragma unroll
        for (int nb = 0; nb < 4; ++nb) {
          float v = c[mm][nb][r] * msk[nb];
          s += v; q += v * v;
        }
        #pragma unroll
        for (int d = 1; d < 16; d <<= 1) {
          s += __shfl_xor(s, d);
          q += __shfl_xor(q, d);
        }
        if (l15 == 0) {
          int f0 = 16 * (NMB * w + mm) + 4 * g + r;
          atomicAdd(&ysum[f0], s);
          atomicAdd(&ysq[f0], q);
        }
      }
  }
}

// ---------------------------------------------------------------------------
// Per-node online scatter-softmax over CSR-contiguous m rows (bf16).
__global__ void node_softmax(const unsigned short* __restrict__ m,
                             const int* __restrict__ off,
                             const float* __restrict__ tptr,
                             float* __restrict__ msg) {
  int gw = (blockIdx.x * 256 + threadIdx.x) >> 6;
  int lane = threadIdx.x & 63;
  if (gw >= NN) return;
  float t = tptr[0];
  int beg = off[gw], end = off[gw + 1];
  float M = -3e38f, S = 0.f, Wn = 0.f;
  int i = beg;
  for (; i + 1 < end; i += 2) {
    float m0 = bf2f(m[(size_t)i * 64 + lane]);
    float m1 = bf2f(m[(size_t)(i + 1) * 64 + lane]);
    float s0 = m0 * t, s1 = m1 * t;
    float Mn = fmaxf(M, fmaxf(s0, s1));
    float c = __expf(M - Mn);
    float p0 = __expf(s0 - Mn), p1 = __expf(s1 - Mn);
    S = S * c + p0 + p1;
    Wn = Wn * c + m0 * p0 + m1 * p1;
    M = Mn;
  }
  if (i < end) {
    float m0 = bf2f(m[(size_t)i * 64 + lane]);
    float s0 = m0 * t;
    float Mn = fmaxf(M, s0);
    float c = __expf(M - Mn);
    float p0 = __expf(s0 - Mn);
    S = S * c + p0;
    Wn = Wn * c + m0 * p0;
    M = Mn;
  }
  msg[(size_t)gw * 64 + lane] = (end > beg) ? (Wn / S) : 0.f;
}

// ---------------------------------------------------------------------------
extern "C" void kernel_launch(void* const* d_in, const int* in_sizes, int n_in,
                              void* d_out, int out_size, void* d_ws, size_t ws_size,
                              hipStream_t stream) {
  const float* x     = (const float*)d_in[0];
  const int*   ei    = (const int*)d_in[1];
  const float* ea    = (const float*)d_in[2];
  const float* gh_w  = (const float*)d_in[3];
  const float* gh_b  = (const float*)d_in[4];
  const float* gv_w  = (const float*)d_in[5];
  const float* gv_b  = (const float*)d_in[6];
  const float* tpar  = (const float*)d_in[7];
  const float* p_w1  = (const float*)d_in[8];
  const float* p_b1  = (const float*)d_in[9];
  const float* p_w2  = (const float*)d_in[10];
  const float* p_b2  = (const float*)d_in[11];
  const float* h_w1  = (const float*)d_in[12];
  const float* h_b1  = (const float*)d_in[13];
  const float* h_g1  = (const float*)d_in[14];
  const float* h_bb1 = (const float*)d_in[15];
  const float* h_w2  = (const float*)d_in[16];
  const float* h_b2  = (const float*)d_in[17];
  const float* h_g2  = (const float*)d_in[18];
  const float* h_bb2 = (const float*)d_in[19];
  const float* h_w3  = (const float*)d_in[20];
  const float* h_b3  = (const float*)d_in[21];
  const float* h_g3  = (const float*)d_in[22];
  const float* h_bb3 = (const float*)d_in[23];
  const float* h_w4  = (const float*)d_in[24];
  const float* h_b4  = (const float*)d_in[25];
  const float* e_w1  = (const float*)d_in[26];
  const float* e_b1  = (const float*)d_in[27];
  const float* e_w2  = (const float*)d_in[28];
  const float* e_b2  = (const float*)d_in[29];

  float* h_out = (float*)d_out;
  float* v_out = (float*)d_out + (size_t)NN * 64;

  const int* src = ei;
  const int* dst = ei + NE;

  char* w = (char*)d_ws;
  // zeroed region: stats (4KB) + cnt + cursor
  float* stats = (float*)w;
  float* xst  = stats;          // [0:64) sum, [64:128) sq
  float* ys1  = stats + 256, *yq1 = stats + 384;
  float* ys2  = stats + 512, *yq2 = stats + 640;
  float* ys3  = stats + 768, *yq3 = stats + 896;
  int* cnt    = (int*)(w + 4096);
  int* cursor = (int*)(w + 4096 + 200704);
  size_t zero_bytes = 4096 + 2 * 200704;

  char* p = w + zero_bytes;
  float* sb = (float*)p; p += 4096;
  float* sbx_s = sb,       *sbx_b = sb + 64;
  float* sbv_s = sb + 128, *sbv_b = sb + 192;
  float* sb1_s = sb + 256, *sb1_b = sb + 384;
  float* sb2_s = sb + 512, *sb2_b = sb + 640;
  float* sb3_s = sb + 768, *sb3_b = sb + 896;
  int* bsum   = (int*)p; p += 1024;
  int* off    = (int*)p; p += 200704;
  int* perm   = (int*)p; p += (size_t)NE * 4;
  int* src_s  = (int*)p; p += (size_t)NE * 4;
  int* dst_s  = (int*)p; p += (size_t)NE * 4;
  float* h    = (float*)p; p += (size_t)NN * 64 * 4;
  float* msg  = (float*)p; p += (size_t)NN * 64 * 4;
  unsigned short* vbf  = (unsigned short*)p; p += (size_t)NE * 64 * 2;
  unsigned short* m_bf = (unsigned short*)p; p += (size_t)NE * 64 * 2;
  unsigned short* PAB  = (unsigned short*)p; p += (size_t)NN * 256 * 2;
  unsigned short* QAB  = (unsigned short*)p; p += (size_t)NN * 256 * 2;
  unsigned short* y1   = (unsigned short*)p; p += (size_t)NN * 128 * 2;
  unsigned short* y2   = (unsigned short*)p; p += (size_t)NN * 128 * 2;
  unsigned short* wpab  = (unsigned short*)p; p += 256 * 64 * 2;
  unsigned short* wqab  = (unsigned short*)p; p += 256 * 64 * 2;
  unsigned short* w1c_p = (unsigned short*)p; p += 128 * 64 * 2;
  unsigned short* w1c_e = (unsigned short*)p; p += 128 * 64 * 2;
  unsigned short* w2f_p = (unsigned short*)p; p += 64 * 128 * 2;
  unsigned short* w2f_e = (unsigned short*)p; p += 64 * 128 * 2;
  unsigned short* h_w1t = (unsigned short*)p; p += 128 * 128 * 2;
  unsigned short* h_w2t = (unsigned short*)p; p += 128 * 128 * 2;
  unsigned short* h_w3t = (unsigned short*)p; p += 128 * 128 * 2;
  unsigned short* h_w4t = (unsigned short*)p; p += 64 * 128 * 2;

  hipMemsetAsync(d_ws, 0, zero_bytes, stream);

  wprep<<<480, 256, 0, stream>>>(p_w1, e_w1, p_w2, e_w2, h_w1, h_w2, h_w3, h_w4,
                                 wpab, wqab, w1c_p, w1c_e, w2f_p, w2f_e,
                                 h_w1t, h_w2t, h_w3t, h_w4t);

  // BN stats
  colstats<64><<<256, 256, 0, stream>>>(x, NN, xst, xst + 64);
  colstats<64><<<1024, 256, 0, stream>>>(ea, NE, stats + 128, stats + 192);

  // CSR (dst)
  count_edges<<<3125, 256, 0, stream>>>(dst, cnt);
  scan_part<<<196, 256, 0, stream>>>(cnt, bsum);
  scan_top<<<1, 256, 0, stream>>>(bsum);
  scan_add<<<196, 256, 0, stream>>>(cnt, bsum, off);
  fill_perm<<<3125, 256, 0, stream>>>(src, dst, off, cursor, perm, src_s, dst_s);

  finalize2<<<2, 64, 0, stream>>>(stats, gh_w, gh_b, gv_w, gv_b, sb);

  // vbf in CSR-permuted order
  bn_scatter<<<25000, 256, 0, stream>>>(ea, sbv_s, sbv_b, perm, vbf);

  // node-side factor: PAB = relu(bn(x)) @ [pW1a|pW1b]; also writes h
  pab_gemm<true, true><<<782, 256, 0, stream>>>(x, sbx_s, sbx_b, wpab, PAB, h);

  // message MLP (CSR order): table0 = dst (pW1a), table1 = src (pW1b)
  edge_mlp3<1><<<12500, 256, 0, stream>>>(vbf, PAB, dst_s, src_s, nullptr,
                                          w1c_p, p_b1, w2f_p, p_b2, (void*)m_bf);

  // scatter-softmax aggregation (contiguous rows)
  node_softmax<<<12500, 256, 0, stream>>>(m_bf, off, tpar, msg);

  // node MLP chain, stats fused into GEMM epilogue
  node_mfma<0, 128, false, true, true><<<782, 256, 0, stream>>>(
      h, msg, nullptr, nullptr, h_w1t, h_b1, (void*)y1, ys1, yq1);
  finalize_sb<<<1, 128, 0, stream>>>(ys1, yq1, 1.0f / NN, h_g1, h_bb1, sb1_s, sb1_b, 128);

  node_mfma<1, 128, true, true, true><<<782, 256, 0, stream>>>(
      y1, nullptr, sb1_s, sb1_b, h_w2t, h_b2, (void*)y2, ys2, yq2);
  finalize_sb<<<1, 128, 0, stream>>>(ys2, yq2, 1.0f / NN, h_g2, h_bb2, sb2_s, sb2_b, 128);

  node_mfma<1, 128, true, true, true><<<782, 256, 0, stream>>>(
      y2, nullptr, sb2_s, sb2_b, h_w3t, h_b3, (void*)y1, ys3, yq3);
  finalize_sb<<<1, 128, 0, stream>>>(ys3, yq3, 1.0f / NN, h_g3, h_bb3, sb3_s, sb3_b, 128);

  node_mfma<1, 64, true, false, false><<<782, 256, 0, stream>>>(
      y1, nullptr, sb3_s, sb3_b, h_w4t, h_b4, (void*)h_out, nullptr, nullptr);

  // node-side factor of edge-output MLP: QAB = relu(h_out) @ [eW1a|eW1b]
  pab_gemm<false, false><<<782, 256, 0, stream>>>(h_out, nullptr, nullptr, wqab, QAB, nullptr);

  // edge output MLP (original order): table0 = src (eW1a), table1 = dst (eW1b)
  edge_mlp3<2><<<12500, 256, 0, stream>>>(vbf, QAB, src, dst, perm,
                                          w1c_e, e_b1, w2f_e, e_b2, (void*)v_out);
}